// Round 1
// baseline (1473.979 us; speedup 1.0000x reference)
//
#include <hip/hip_runtime.h>
#include <hip/hip_bf16.h>
#include <math.h>

#define IN_FEATS 128
#define HIDDEN   256
#define CLASSES  41
#define CPAD     64

// ---------------- scatter1: agg1[dst] += x[src]; deg[dst] += 1 ----------------
__global__ void __launch_bounds__(256)
scatter1_kernel(const float* __restrict__ x, const int* __restrict__ src,
                const int* __restrict__ dst, float* __restrict__ agg1,
                float* __restrict__ deg, int E) {
    int t = blockIdx.x * blockDim.x + threadIdx.x;
    int e = t >> 6;
    int lane = t & 63;
    if (e >= E) return;
    int s = src[e], d = dst[e];
    const float* xr = x + (size_t)s * IN_FEATS;
    float* ar = agg1 + (size_t)d * IN_FEATS;
    atomicAdd(&ar[lane],      xr[lane]);
    atomicAdd(&ar[lane + 64], xr[lane + 64]);
    if (lane == 0) atomicAdd(&deg[d], 1.0f);
}

// ---------------- gemm1: h1 = relu((agg1/deg) @ W1l + b1 + x @ W1r) ----------
#define G1_ROWS 8
__global__ void __launch_bounds__(256)
gemm1_kernel(const float* __restrict__ agg1, const float* __restrict__ x,
             const float* __restrict__ deg, const float* __restrict__ Wl,
             const float* __restrict__ Wr, const float* __restrict__ b,
             float* __restrict__ h1, int N) {
    __shared__ float a_lds[G1_ROWS][IN_FEATS];
    __shared__ float x_lds[G1_ROWS][IN_FEATS];
    int n0 = blockIdx.x * G1_ROWS;
    for (int i = threadIdx.x; i < G1_ROWS * IN_FEATS; i += 256) {
        int r = i >> 7, k = i & 127;
        int n = n0 + r;
        if (n < N) {
            float sc = 1.0f / fmaxf(deg[n], 1.0f);
            a_lds[r][k] = agg1[(size_t)n * IN_FEATS + k] * sc;
            x_lds[r][k] = x[(size_t)n * IN_FEATS + k];
        } else {
            a_lds[r][k] = 0.0f;
            x_lds[r][k] = 0.0f;
        }
    }
    __syncthreads();
    int c = threadIdx.x;  // output column 0..255
    float acc[G1_ROWS];
#pragma unroll
    for (int r = 0; r < G1_ROWS; ++r) acc[r] = 0.0f;
    for (int k = 0; k < IN_FEATS; ++k) {
        float wl = Wl[k * HIDDEN + c];
        float wr = Wr[k * HIDDEN + c];
#pragma unroll
        for (int r = 0; r < G1_ROWS; ++r)
            acc[r] = fmaf(a_lds[r][k], wl, fmaf(x_lds[r][k], wr, acc[r]));
    }
    float bias = b[c];
#pragma unroll
    for (int r = 0; r < G1_ROWS; ++r) {
        int n = n0 + r;
        if (n < N) h1[(size_t)n * HIDDEN + c] = fmaxf(acc[r] + bias, 0.0f);
    }
}

// ------- gemm2: z = h1 @ W2l ; r = h1 @ W2r + b2 (both [N, CPAD] padded) -----
__global__ void __launch_bounds__(256)
gemm2_kernel(const float* __restrict__ h1, const float* __restrict__ W2l,
             const float* __restrict__ W2r, const float* __restrict__ b2,
             float* __restrict__ z, float* __restrict__ rbuf, int N) {
    __shared__ float h_lds[32][HIDDEN];
    int nblk = blockIdx.x * 32;
    for (int i = threadIdx.x; i < 32 * HIDDEN; i += 256) {
        int nn = i >> 8, k = i & 255;
        int n = nblk + nn;
        h_lds[nn][k] = (n < N) ? h1[(size_t)n * HIDDEN + k] : 0.0f;
    }
    __syncthreads();
    int w = threadIdx.x >> 6;
    int lane = threadIdx.x & 63;
    int jbase = w * 8;
    if (lane < CLASSES) {
        float az[8], ar[8];
#pragma unroll
        for (int j = 0; j < 8; ++j) { az[j] = 0.0f; ar[j] = 0.0f; }
        for (int k = 0; k < HIDDEN; k += 4) {
            float wl0 = W2l[(k + 0) * CLASSES + lane];
            float wl1 = W2l[(k + 1) * CLASSES + lane];
            float wl2 = W2l[(k + 2) * CLASSES + lane];
            float wl3 = W2l[(k + 3) * CLASSES + lane];
            float wr0 = W2r[(k + 0) * CLASSES + lane];
            float wr1 = W2r[(k + 1) * CLASSES + lane];
            float wr2 = W2r[(k + 2) * CLASSES + lane];
            float wr3 = W2r[(k + 3) * CLASSES + lane];
#pragma unroll
            for (int j = 0; j < 8; ++j) {
                float4 h4 = *(const float4*)&h_lds[jbase + j][k];
                az[j] = fmaf(h4.x, wl0, az[j]);
                az[j] = fmaf(h4.y, wl1, az[j]);
                az[j] = fmaf(h4.z, wl2, az[j]);
                az[j] = fmaf(h4.w, wl3, az[j]);
                ar[j] = fmaf(h4.x, wr0, ar[j]);
                ar[j] = fmaf(h4.y, wr1, ar[j]);
                ar[j] = fmaf(h4.z, wr2, ar[j]);
                ar[j] = fmaf(h4.w, wr3, ar[j]);
            }
        }
        float bb = b2[lane];
#pragma unroll
        for (int j = 0; j < 8; ++j) {
            int n = nblk + jbase + j;
            if (n < N) {
                z[(size_t)n * CPAD + lane]    = az[j];
                rbuf[(size_t)n * CPAD + lane] = ar[j] + bb;
            }
        }
    }
}

// ---------------- scatter2: out_acc[dst] += z[src] ---------------------------
__global__ void __launch_bounds__(256)
scatter2_kernel(const float* __restrict__ z, const int* __restrict__ src,
                const int* __restrict__ dst, float* __restrict__ out_acc, int E) {
    int t = blockIdx.x * blockDim.x + threadIdx.x;
    int e = t >> 6;
    int c = t & 63;
    if (e >= E) return;
    if (c < CLASSES) {
        atomicAdd(&out_acc[(size_t)dst[e] * CPAD + c],
                  z[(size_t)src[e] * CPAD + c]);
    }
}

// ---------------- final: out = log_softmax(out_acc/deg + r) ------------------
__global__ void __launch_bounds__(256)
final_kernel(const float* __restrict__ out_acc, const float* __restrict__ rbuf,
             const float* __restrict__ deg, float* __restrict__ out, int N) {
    int t = blockIdx.x * blockDim.x + threadIdx.x;
    int n = t >> 6;
    int lane = t & 63;
    if (n >= N) return;
    float inv = 1.0f / fmaxf(deg[n], 1.0f);
    float v = -INFINITY;
    if (lane < CLASSES)
        v = out_acc[(size_t)n * CPAD + lane] * inv + rbuf[(size_t)n * CPAD + lane];
    float m = v;
#pragma unroll
    for (int off = 32; off; off >>= 1) m = fmaxf(m, __shfl_xor(m, off));
    float e = (lane < CLASSES) ? expf(v - m) : 0.0f;
    float s = e;
#pragma unroll
    for (int off = 32; off; off >>= 1) s += __shfl_xor(s, off);
    if (lane < CLASSES)
        out[(size_t)n * CLASSES + lane] = v - m - logf(s);
}

extern "C" void kernel_launch(void* const* d_in, const int* in_sizes, int n_in,
                              void* d_out, int out_size, void* d_ws, size_t ws_size,
                              hipStream_t stream) {
    const float* x   = (const float*)d_in[0];
    const int*   ei  = (const int*)d_in[1];
    const float* W1l = (const float*)d_in[2];
    const float* W1r = (const float*)d_in[3];
    const float* b1  = (const float*)d_in[4];
    const float* W2l = (const float*)d_in[5];
    const float* W2r = (const float*)d_in[6];
    const float* b2  = (const float*)d_in[7];
    float* out = (float*)d_out;

    int N = in_sizes[0] / IN_FEATS;
    int E = in_sizes[1] / 2;
    const int* src = ei;
    const int* dst = ei + E;

    // ws layout (floats):
    // [0, N)          deg
    // [N, 65N)        out_acc (N x 64)
    // [65N, 193N)     agg1 (N x 128); later overlaid by z (N x 64) + r (N x 64)
    // [193N, 449N)    h1 (N x 256)
    float* ws      = (float*)d_ws;
    float* deg     = ws;
    float* out_acc = ws + (size_t)N;
    float* agg1    = ws + (size_t)65 * N;
    float* z       = agg1;                    // reuse after gemm1
    float* rbuf    = agg1 + (size_t)64 * N;   // reuse after gemm1
    float* h1      = ws + (size_t)193 * N;

    // zero deg + out_acc + agg1 (contiguous prefix)
    hipMemsetAsync(d_ws, 0, (size_t)193 * N * sizeof(float), stream);

    {   // one wave per edge
        long long threads = (long long)E * 64;
        int blocks = (int)((threads + 255) / 256);
        scatter1_kernel<<<blocks, 256, 0, stream>>>(x, src, dst, agg1, deg, E);
    }
    gemm1_kernel<<<(N + G1_ROWS - 1) / G1_ROWS, 256, 0, stream>>>(
        agg1, x, deg, W1l, W1r, b1, h1, N);
    gemm2_kernel<<<(N + 31) / 32, 256, 0, stream>>>(h1, W2l, W2r, b2, z, rbuf, N);
    {
        long long threads = (long long)E * 64;
        int blocks = (int)((threads + 255) / 256);
        scatter2_kernel<<<blocks, 256, 0, stream>>>(z, src, dst, out_acc, E);
    }
    {
        long long threads = (long long)N * 64;
        int blocks = (int)((threads + 255) / 256);
        final_kernel<<<blocks, 256, 0, stream>>>(out_acc, rbuf, deg, out, N);
    }
}

// Round 2
// 849.697 us; speedup vs baseline: 1.7347x; 1.7347x over previous
//
#include <hip/hip_runtime.h>
#include <hip/hip_bf16.h>
#include <math.h>

#define IN_FEATS 128
#define HIDDEN   256
#define CLASSES  41
#define CPAD     64
#define SCAN_BLK 1024   // elements per scan block (256 threads x 4)

// ---------------- hist: deg_i[dst]++ ----------------------------------------
__global__ void __launch_bounds__(256)
hist_kernel(const int* __restrict__ dst, int* __restrict__ deg_i, int E) {
    int e = blockIdx.x * blockDim.x + threadIdx.x;
    if (e < E) atomicAdd(&deg_i[dst[e]], 1);
}

// ---------------- scan (3-phase exclusive prefix sum over deg_i) ------------
__global__ void __launch_bounds__(256)
scan1_kernel(const int* __restrict__ deg_i, int* __restrict__ row_start,
             int* __restrict__ blk_sums, int N) {
    __shared__ int lds[256];
    int base = blockIdx.x * SCAN_BLK;
    int t = threadIdx.x;
    int v[4];
    int s = 0;
#pragma unroll
    for (int i = 0; i < 4; ++i) {
        int idx = base + t * 4 + i;
        v[i] = (idx < N) ? deg_i[idx] : 0;
        s += v[i];
    }
    lds[t] = s;
    __syncthreads();
    for (int off = 1; off < 256; off <<= 1) {
        int val = lds[t];
        int add = (t >= off) ? lds[t - off] : 0;
        __syncthreads();
        lds[t] = val + add;
        __syncthreads();
    }
    if (t == 255) blk_sums[blockIdx.x] = lds[255];
    int run = (t == 0) ? 0 : lds[t - 1];
#pragma unroll
    for (int i = 0; i < 4; ++i) {
        int idx = base + t * 4 + i;
        if (idx < N) row_start[idx] = run;
        run += v[i];
    }
}

__global__ void __launch_bounds__(256)
scan2_kernel(int* __restrict__ blk_sums, int nb) {
    __shared__ int lds[256];
    int t = threadIdx.x;
    lds[t] = (t < nb) ? blk_sums[t] : 0;
    __syncthreads();
    for (int off = 1; off < 256; off <<= 1) {
        int val = lds[t];
        int add = (t >= off) ? lds[t - off] : 0;
        __syncthreads();
        lds[t] = val + add;
        __syncthreads();
    }
    if (t < nb) blk_sums[t] = (t == 0) ? 0 : lds[t - 1];
}

__global__ void __launch_bounds__(256)
scan3_kernel(int* __restrict__ row_start, const int* __restrict__ blk_sums, int N) {
    int idx = blockIdx.x * blockDim.x + threadIdx.x;
    if (idx < N) row_start[idx] += blk_sums[idx / SCAN_BLK];
}

// ---------------- fill: csr_src[row_start[dst] + pos++] = src ---------------
__global__ void __launch_bounds__(256)
fill_kernel(const int* __restrict__ src, const int* __restrict__ dst,
            const int* __restrict__ row_start, int* __restrict__ cursor,
            int* __restrict__ csr_src, int E) {
    int e = blockIdx.x * blockDim.x + threadIdx.x;
    if (e >= E) return;
    int d = dst[e];
    int p = atomicAdd(&cursor[d], 1);
    csr_src[row_start[d] + p] = src[e];
}

// ---------------- gather1: aggm[n] = mean_{s in N(n)} x[s] ------------------
__global__ void __launch_bounds__(256)
gather1_kernel(const float* __restrict__ x, const int* __restrict__ row_start,
               const int* __restrict__ deg_i, const int* __restrict__ csr_src,
               float* __restrict__ aggm, int N) {
    int wid = (blockIdx.x * 256 + threadIdx.x) >> 6;
    int lane = threadIdx.x & 63;
    if (wid >= N) return;
    int rs = row_start[wid];
    int d = deg_i[wid];
    const float2* xp = (const float2*)x;
    float ax = 0.0f, ay = 0.0f;
    int i = 0;
    for (; i + 2 <= d; i += 2) {
        int s0 = csr_src[rs + i];
        int s1 = csr_src[rs + i + 1];
        float2 v0 = xp[(size_t)s0 * 64 + lane];
        float2 v1 = xp[(size_t)s1 * 64 + lane];
        ax += v0.x + v1.x;
        ay += v0.y + v1.y;
    }
    if (i < d) {
        int s0 = csr_src[rs + i];
        float2 v0 = xp[(size_t)s0 * 64 + lane];
        ax += v0.x;
        ay += v0.y;
    }
    float inv = 1.0f / fmaxf((float)d, 1.0f);
    ((float2*)aggm)[(size_t)wid * 64 + lane] = make_float2(ax * inv, ay * inv);
}

// ---------------- gemm1: h1 = relu(aggm @ W1l + b1 + x @ W1r) ---------------
#define G1_ROWS 8
__global__ void __launch_bounds__(256)
gemm1_kernel(const float* __restrict__ aggm, const float* __restrict__ x,
             const float* __restrict__ Wl, const float* __restrict__ Wr,
             const float* __restrict__ b, float* __restrict__ h1, int N) {
    __shared__ float a_lds[G1_ROWS][IN_FEATS];
    __shared__ float x_lds[G1_ROWS][IN_FEATS];
    int n0 = blockIdx.x * G1_ROWS;
    for (int i = threadIdx.x; i < G1_ROWS * IN_FEATS; i += 256) {
        int r = i >> 7, k = i & 127;
        int n = n0 + r;
        a_lds[r][k] = (n < N) ? aggm[(size_t)n * IN_FEATS + k] : 0.0f;
        x_lds[r][k] = (n < N) ? x[(size_t)n * IN_FEATS + k] : 0.0f;
    }
    __syncthreads();
    int c = threadIdx.x;
    float acc[G1_ROWS];
#pragma unroll
    for (int r = 0; r < G1_ROWS; ++r) acc[r] = 0.0f;
    for (int k = 0; k < IN_FEATS; ++k) {
        float wl = Wl[k * HIDDEN + c];
        float wr = Wr[k * HIDDEN + c];
#pragma unroll
        for (int r = 0; r < G1_ROWS; ++r)
            acc[r] = fmaf(a_lds[r][k], wl, fmaf(x_lds[r][k], wr, acc[r]));
    }
    float bias = b[c];
#pragma unroll
    for (int r = 0; r < G1_ROWS; ++r) {
        int n = n0 + r;
        if (n < N) h1[(size_t)n * HIDDEN + c] = fmaxf(acc[r] + bias, 0.0f);
    }
}

// ------- gemm2: z = h1 @ W2l ; r = h1 @ W2r + b2 (both [N, CPAD] padded) -----
__global__ void __launch_bounds__(256)
gemm2_kernel(const float* __restrict__ h1, const float* __restrict__ W2l,
             const float* __restrict__ W2r, const float* __restrict__ b2,
             float* __restrict__ z, float* __restrict__ rbuf, int N) {
    __shared__ float h_lds[32][HIDDEN];
    int nblk = blockIdx.x * 32;
    for (int i = threadIdx.x; i < 32 * HIDDEN; i += 256) {
        int nn = i >> 8, k = i & 255;
        int n = nblk + nn;
        h_lds[nn][k] = (n < N) ? h1[(size_t)n * HIDDEN + k] : 0.0f;
    }
    __syncthreads();
    int w = threadIdx.x >> 6;
    int lane = threadIdx.x & 63;
    int jbase = w * 8;
    if (lane < CLASSES) {
        float az[8], ar[8];
#pragma unroll
        for (int j = 0; j < 8; ++j) { az[j] = 0.0f; ar[j] = 0.0f; }
        for (int k = 0; k < HIDDEN; k += 4) {
            float wl0 = W2l[(k + 0) * CLASSES + lane];
            float wl1 = W2l[(k + 1) * CLASSES + lane];
            float wl2 = W2l[(k + 2) * CLASSES + lane];
            float wl3 = W2l[(k + 3) * CLASSES + lane];
            float wr0 = W2r[(k + 0) * CLASSES + lane];
            float wr1 = W2r[(k + 1) * CLASSES + lane];
            float wr2 = W2r[(k + 2) * CLASSES + lane];
            float wr3 = W2r[(k + 3) * CLASSES + lane];
#pragma unroll
            for (int j = 0; j < 8; ++j) {
                float4 h4 = *(const float4*)&h_lds[jbase + j][k];
                az[j] = fmaf(h4.x, wl0, az[j]);
                az[j] = fmaf(h4.y, wl1, az[j]);
                az[j] = fmaf(h4.z, wl2, az[j]);
                az[j] = fmaf(h4.w, wl3, az[j]);
                ar[j] = fmaf(h4.x, wr0, ar[j]);
                ar[j] = fmaf(h4.y, wr1, ar[j]);
                ar[j] = fmaf(h4.z, wr2, ar[j]);
                ar[j] = fmaf(h4.w, wr3, ar[j]);
            }
        }
        float bb = b2[lane];
#pragma unroll
        for (int j = 0; j < 8; ++j) {
            int n = nblk + jbase + j;
            if (n < N) {
                z[(size_t)n * CPAD + lane]    = az[j];
                rbuf[(size_t)n * CPAD + lane] = ar[j] + bb;
            }
        }
    }
}

// -------- gather2+final: out = log_softmax(mean_{s}(z[s]) + rbuf) -----------
__global__ void __launch_bounds__(256)
gather2_kernel(const float* __restrict__ z, const float* __restrict__ rbuf,
               const int* __restrict__ row_start, const int* __restrict__ deg_i,
               const int* __restrict__ csr_src, float* __restrict__ out, int N) {
    int wid = (blockIdx.x * 256 + threadIdx.x) >> 6;
    int lane = threadIdx.x & 63;
    if (wid >= N) return;
    int rs = row_start[wid];
    int d = deg_i[wid];
    float acc = 0.0f;
    int i = 0;
    for (; i + 2 <= d; i += 2) {
        int s0 = csr_src[rs + i];
        int s1 = csr_src[rs + i + 1];
        acc += z[(size_t)s0 * CPAD + lane] + z[(size_t)s1 * CPAD + lane];
    }
    if (i < d) acc += z[(size_t)csr_src[rs + i] * CPAD + lane];
    float inv = 1.0f / fmaxf((float)d, 1.0f);
    float v = -INFINITY;
    if (lane < CLASSES)
        v = acc * inv + rbuf[(size_t)wid * CPAD + lane];
    float m = v;
#pragma unroll
    for (int off = 32; off; off >>= 1) m = fmaxf(m, __shfl_xor(m, off));
    float e = (lane < CLASSES) ? expf(v - m) : 0.0f;
    float s = e;
#pragma unroll
    for (int off = 32; off; off >>= 1) s += __shfl_xor(s, off);
    if (lane < CLASSES)
        out[(size_t)wid * CLASSES + lane] = v - m - logf(s);
}

extern "C" void kernel_launch(void* const* d_in, const int* in_sizes, int n_in,
                              void* d_out, int out_size, void* d_ws, size_t ws_size,
                              hipStream_t stream) {
    const float* x   = (const float*)d_in[0];
    const int*   ei  = (const int*)d_in[1];
    const float* W1l = (const float*)d_in[2];
    const float* W1r = (const float*)d_in[3];
    const float* b1  = (const float*)d_in[4];
    const float* W2l = (const float*)d_in[5];
    const float* W2r = (const float*)d_in[6];
    const float* b2  = (const float*)d_in[7];
    float* out = (float*)d_out;

    int N = in_sizes[0] / IN_FEATS;
    int E = in_sizes[1] / 2;
    const int* src = ei;
    const int* dst = ei + E;

    // ws layout:
    // ints:   [deg_i N][cursor N][blk_sums 256][row_start N][csr_src E]
    // floats: [aggm 128N (later z 64N + rbuf 64N)][h1 256N]
    int* ws_i      = (int*)d_ws;
    int* deg_i     = ws_i;
    int* cursor    = ws_i + (size_t)N;
    int* blk_sums  = ws_i + (size_t)2 * N;
    int* row_start = ws_i + (size_t)2 * N + 256;
    int* csr_src   = ws_i + (size_t)3 * N + 256;
    size_t fofs = ((size_t)3 * N + 256 + (size_t)E + 3) & ~(size_t)3;
    float* aggm = (float*)d_ws + fofs;
    float* z    = aggm;                      // overlay after gemm1
    float* rbuf = aggm + (size_t)64 * N;     // overlay after gemm1
    float* h1   = aggm + (size_t)128 * N;

    // zero deg_i + cursor + blk_sums (contiguous)
    hipMemsetAsync(deg_i, 0, ((size_t)2 * N + 256) * sizeof(int), stream);

    hist_kernel<<<(E + 255) / 256, 256, 0, stream>>>(dst, deg_i, E);

    int nscan = (N + SCAN_BLK - 1) / SCAN_BLK;   // 98 for N=100000
    scan1_kernel<<<nscan, 256, 0, stream>>>(deg_i, row_start, blk_sums, N);
    scan2_kernel<<<1, 256, 0, stream>>>(blk_sums, nscan);
    scan3_kernel<<<(N + 255) / 256, 256, 0, stream>>>(row_start, blk_sums, N);

    fill_kernel<<<(E + 255) / 256, 256, 0, stream>>>(src, dst, row_start, cursor,
                                                     csr_src, E);

    {
        long long threads = (long long)N * 64;
        gather1_kernel<<<(int)((threads + 255) / 256), 256, 0, stream>>>(
            x, row_start, deg_i, csr_src, aggm, N);
    }
    gemm1_kernel<<<(N + G1_ROWS - 1) / G1_ROWS, 256, 0, stream>>>(
        aggm, x, W1l, W1r, b1, h1, N);
    gemm2_kernel<<<(N + 31) / 32, 256, 0, stream>>>(h1, W2l, W2r, b2, z, rbuf, N);
    {
        long long threads = (long long)N * 64;
        gather2_kernel<<<(int)((threads + 255) / 256), 256, 0, stream>>>(
            z, rbuf, row_start, deg_i, csr_src, out, N);
    }
}

// Round 3
// 459.685 us; speedup vs baseline: 3.2065x; 1.8484x over previous
//
#include <hip/hip_runtime.h>
#include <math.h>

#define IN_FEATS 128
#define HIDDEN   256
#define CLASSES  41
#define CPAD     64
#define SCAN_BLK 1024
#define LDA      264   // 256 + 8 pad (bf16 elems): row stride 528B = 4 dwords mod 32 banks

typedef __attribute__((ext_vector_type(8))) short short8;
typedef __attribute__((ext_vector_type(4))) float f32x4;

__device__ __forceinline__ unsigned short f2bf(float f) {
    union { float f; unsigned u; } v; v.f = f;
    unsigned r = v.u + 0x7FFF + ((v.u >> 16) & 1);
    return (unsigned short)(r >> 16);
}
__device__ __forceinline__ float bf2f(unsigned short h) {
    union { unsigned u; float f; } v; v.u = ((unsigned)h) << 16;
    return v.f;
}

// ---------------- hist: deg_i[dst]++ ----------------------------------------
__global__ void __launch_bounds__(256)
hist_kernel(const int* __restrict__ dst, int* __restrict__ deg_i, int E) {
    int e = blockIdx.x * blockDim.x + threadIdx.x;
    if (e < E) atomicAdd(&deg_i[dst[e]], 1);
}

// ---------------- 3-phase exclusive scan ------------------------------------
__global__ void __launch_bounds__(256)
scan1_kernel(const int* __restrict__ deg_i, int* __restrict__ row_start,
             int* __restrict__ blk_sums, int N) {
    __shared__ int lds[256];
    int base = blockIdx.x * SCAN_BLK;
    int t = threadIdx.x;
    int v[4];
    int s = 0;
#pragma unroll
    for (int i = 0; i < 4; ++i) {
        int idx = base + t * 4 + i;
        v[i] = (idx < N) ? deg_i[idx] : 0;
        s += v[i];
    }
    lds[t] = s;
    __syncthreads();
    for (int off = 1; off < 256; off <<= 1) {
        int val = lds[t];
        int add = (t >= off) ? lds[t - off] : 0;
        __syncthreads();
        lds[t] = val + add;
        __syncthreads();
    }
    if (t == 255) blk_sums[blockIdx.x] = lds[255];
    int run = (t == 0) ? 0 : lds[t - 1];
#pragma unroll
    for (int i = 0; i < 4; ++i) {
        int idx = base + t * 4 + i;
        if (idx < N) row_start[idx] = run;
        run += v[i];
    }
}

__global__ void __launch_bounds__(256)
scan2_kernel(int* __restrict__ blk_sums, int nb) {
    __shared__ int lds[256];
    int t = threadIdx.x;
    lds[t] = (t < nb) ? blk_sums[t] : 0;
    __syncthreads();
    for (int off = 1; off < 256; off <<= 1) {
        int val = lds[t];
        int add = (t >= off) ? lds[t - off] : 0;
        __syncthreads();
        lds[t] = val + add;
        __syncthreads();
    }
    if (t < nb) blk_sums[t] = (t == 0) ? 0 : lds[t - 1];
}

__global__ void __launch_bounds__(256)
scan3_kernel(int* __restrict__ row_start, const int* __restrict__ blk_sums, int N) {
    int idx = blockIdx.x * blockDim.x + threadIdx.x;
    if (idx < N) row_start[idx] += blk_sums[idx / SCAN_BLK];
}

// ---------------- fill: csr_src[row_start[dst] + pos++] = src ---------------
__global__ void __launch_bounds__(256)
fill_kernel(const int* __restrict__ src, const int* __restrict__ dst,
            const int* __restrict__ row_start, int* __restrict__ cursor,
            int* __restrict__ csr_src, int E) {
    int e = blockIdx.x * blockDim.x + threadIdx.x;
    if (e >= E) return;
    int d = dst[e];
    int p = atomicAdd(&cursor[d], 1);
    csr_src[row_start[d] + p] = src[e];
}

// ---------------- xbf: x -> bf16 --------------------------------------------
__global__ void __launch_bounds__(256)
xbf_kernel(const float* __restrict__ x, unsigned short* __restrict__ xbf, long n4) {
    long i = (long)blockIdx.x * 256 + threadIdx.x;
    if (i >= n4) return;
    float4 v = *(const float4*)(x + i * 4);
    ushort4 o;
    o.x = f2bf(v.x); o.y = f2bf(v.y); o.z = f2bf(v.z); o.w = f2bf(v.w);
    *(ushort4*)(xbf + i * 4) = o;
}

// ------- prep: pack [W1l;W1r] -> Bp1 (256x256) and [W2l|W2r] -> Bp2 (256x96) -
// frag layout: lane l holds B[8*(l>>4)+j][l&15] -> store (k,c) at
//   ((k>>5)*NC + c)*32 + ((k&31)>>3)*8 + (k&7)
__global__ void __launch_bounds__(256)
prep_kernel(const float* __restrict__ W1l, const float* __restrict__ W1r,
            const float* __restrict__ W2l, const float* __restrict__ W2r,
            unsigned short* __restrict__ Bp1, unsigned short* __restrict__ Bp2) {
    int idx = blockIdx.x * 256 + threadIdx.x;
    if (idx < 256 * 256) {
        int k = idx >> 8, c = idx & 255;
        float v = (k < 128) ? W1l[k * 256 + c] : W1r[(k - 128) * 256 + c];
        Bp1[((k >> 5) * 256 + c) * 32 + ((k & 31) >> 3) * 8 + (k & 7)] = f2bf(v);
    } else {
        int j = idx - 65536;
        if (j < 256 * 96) {
            int k = j / 96, c = j % 96;
            float v = 0.0f;
            if (c < 41) v = W2l[k * 41 + c];
            else if (c >= 48 && c < 89) v = W2r[k * 41 + (c - 48)];
            Bp2[((k >> 5) * 96 + c) * 32 + ((k & 31) >> 3) * 8 + (k & 7)] = f2bf(v);
        }
    }
}

// ---------------- gather1: aggm_bf[n] = bf16(mean_{s} xbf[s]) ---------------
__global__ void __launch_bounds__(256)
gather1_kernel(const unsigned short* __restrict__ xbf,
               const int* __restrict__ row_start, const int* __restrict__ deg_i,
               const int* __restrict__ csr_src, unsigned short* __restrict__ aggm,
               int N) {
    int wid = (blockIdx.x * 256 + threadIdx.x) >> 6;
    int lane = threadIdx.x & 63;
    if (wid >= N) return;
    int rs = row_start[wid];
    int d = deg_i[wid];
    const unsigned* xp = (const unsigned*)xbf;   // 2 bf16 / u32
    float ax = 0.0f, ay = 0.0f;
    int i = 0;
    for (; i + 2 <= d; i += 2) {
        int s0 = csr_src[rs + i];
        int s1 = csr_src[rs + i + 1];
        unsigned u0 = xp[(size_t)s0 * 64 + lane];
        unsigned u1 = xp[(size_t)s1 * 64 + lane];
        ax += bf2f((unsigned short)(u0 & 0xffff)) + bf2f((unsigned short)(u1 & 0xffff));
        ay += bf2f((unsigned short)(u0 >> 16))    + bf2f((unsigned short)(u1 >> 16));
    }
    if (i < d) {
        unsigned u0 = xp[(size_t)csr_src[rs + i] * 64 + lane];
        ax += bf2f((unsigned short)(u0 & 0xffff));
        ay += bf2f((unsigned short)(u0 >> 16));
    }
    float inv = 1.0f / fmaxf((float)d, 1.0f);
    unsigned out = ((unsigned)f2bf(ay * inv) << 16) | (unsigned)f2bf(ax * inv);
    ((unsigned*)aggm)[(size_t)wid * 64 + lane] = out;
}

// ------- mgemm1: h1 = bf16(relu([aggm|xbf] @ Bp1 + b1)), MFMA ---------------
__global__ void __launch_bounds__(256)
mgemm1_kernel(const unsigned short* __restrict__ aggm,
              const unsigned short* __restrict__ xbf,
              const unsigned short* __restrict__ Bp1, const float* __restrict__ b1,
              unsigned short* __restrict__ h1, int N) {
    __shared__ __align__(16) unsigned short alds[64 * LDA];
    int n0 = blockIdx.x * 64;
    int t = threadIdx.x;
#pragma unroll
    for (int i = 0; i < 8; ++i) {
        int cid = t + i * 256;           // 2048 chunks of 16B
        int row = cid >> 5, c16 = cid & 31;
        int gr = n0 + row;
        uint4 v = make_uint4(0, 0, 0, 0);
        if (gr < N) {
            const unsigned short* srcp = (c16 < 16)
                ? (aggm + (size_t)gr * 128 + c16 * 8)
                : (xbf  + (size_t)gr * 128 + (c16 - 16) * 8);
            v = *(const uint4*)srcp;
        }
        *(uint4*)&alds[row * LDA + c16 * 8] = v;
    }
    __syncthreads();
    int wid = t >> 6, lane = t & 63;
    int l15 = lane & 15, g = lane >> 4;
    int col0 = wid * 64;
    f32x4 acc[4][4];
#pragma unroll
    for (int mf = 0; mf < 4; ++mf)
#pragma unroll
        for (int nf = 0; nf < 4; ++nf) acc[mf][nf] = (f32x4)(0.0f);
    for (int ks = 0; ks < 8; ++ks) {
        short8 af[4], bfr[4];
#pragma unroll
        for (int mf = 0; mf < 4; ++mf)
            af[mf] = *(const short8*)&alds[(mf * 16 + l15) * LDA + ks * 32 + g * 8];
#pragma unroll
        for (int nf = 0; nf < 4; ++nf)
            bfr[nf] = *(const short8*)&Bp1[((size_t)ks * 256 + col0 + nf * 16 + l15) * 32 + g * 8];
#pragma unroll
        for (int mf = 0; mf < 4; ++mf)
#pragma unroll
            for (int nf = 0; nf < 4; ++nf)
                acc[mf][nf] = __builtin_amdgcn_mfma_f32_16x16x32_bf16(
                    af[mf], bfr[nf], acc[mf][nf], 0, 0, 0);
    }
    float bc[4];
#pragma unroll
    for (int nf = 0; nf < 4; ++nf) bc[nf] = b1[col0 + nf * 16 + l15];
#pragma unroll
    for (int mf = 0; mf < 4; ++mf) {
        int rowb = n0 + mf * 16 + g * 4;
#pragma unroll
        for (int r = 0; r < 4; ++r) {
            int row = rowb + r;
            if (row < N) {
#pragma unroll
                for (int nf = 0; nf < 4; ++nf)
                    h1[(size_t)row * 256 + col0 + nf * 16 + l15] =
                        f2bf(fmaxf(acc[mf][nf][r] + bc[nf], 0.0f));
            }
        }
    }
}

// ------- mgemm2: z = h1@W2l ; r = h1@W2r + b2 via MFMA (B packed Bp2) -------
__global__ void __launch_bounds__(256)
mgemm2_kernel(const unsigned short* __restrict__ h1,
              const unsigned short* __restrict__ Bp2, const float* __restrict__ b2,
              float* __restrict__ z, float* __restrict__ rbuf, int N) {
    __shared__ __align__(16) unsigned short alds[64 * LDA];
    int n0 = blockIdx.x * 64;
    int t = threadIdx.x;
#pragma unroll
    for (int i = 0; i < 8; ++i) {
        int cid = t + i * 256;
        int row = cid >> 5, c16 = cid & 31;
        int gr = n0 + row;
        uint4 v = make_uint4(0, 0, 0, 0);
        if (gr < N) v = *(const uint4*)(h1 + (size_t)gr * 256 + c16 * 8);
        *(uint4*)&alds[row * LDA + c16 * 8] = v;
    }
    __syncthreads();
    int wid = t >> 6, lane = t & 63;
    int l15 = lane & 15, g = lane >> 4;
    int wr = wid >> 1, wc = wid & 1;    // 2x2 wave grid: 32 rows x 48 cols each
    f32x4 acc[2][3];
#pragma unroll
    for (int mf = 0; mf < 2; ++mf)
#pragma unroll
        for (int nf = 0; nf < 3; ++nf) acc[mf][nf] = (f32x4)(0.0f);
    for (int ks = 0; ks < 8; ++ks) {
        short8 af[2], bfr[3];
#pragma unroll
        for (int mf = 0; mf < 2; ++mf)
            af[mf] = *(const short8*)&alds[(wr * 32 + mf * 16 + l15) * LDA + ks * 32 + g * 8];
#pragma unroll
        for (int nf = 0; nf < 3; ++nf)
            bfr[nf] = *(const short8*)&Bp2[((size_t)ks * 96 + wc * 48 + nf * 16 + l15) * 32 + g * 8];
#pragma unroll
        for (int mf = 0; mf < 2; ++mf)
#pragma unroll
            for (int nf = 0; nf < 3; ++nf)
                acc[mf][nf] = __builtin_amdgcn_mfma_f32_16x16x32_bf16(
                    af[mf], bfr[nf], acc[mf][nf], 0, 0, 0);
    }
#pragma unroll
    for (int nf = 0; nf < 3; ++nf) {
        int col = wc * 48 + nf * 16 + l15;
        float bb = (col >= 48 && col < 89) ? b2[col - 48] : 0.0f;
#pragma unroll
        for (int mf = 0; mf < 2; ++mf) {
            int rowb = n0 + wr * 32 + mf * 16 + g * 4;
#pragma unroll
            for (int r = 0; r < 4; ++r) {
                int row = rowb + r;
                if (row < N) {
                    float v = acc[mf][nf][r];
                    if (col < 41)                 z[(size_t)row * CPAD + col] = v;
                    else if (col >= 48 && col < 89) rbuf[(size_t)row * CPAD + (col - 48)] = v + bb;
                }
            }
        }
    }
}

// -------- gather2+final: out = log_softmax(mean_{s}(z[s]) + rbuf) -----------
__global__ void __launch_bounds__(256)
gather2_kernel(const float* __restrict__ z, const float* __restrict__ rbuf,
               const int* __restrict__ row_start, const int* __restrict__ deg_i,
               const int* __restrict__ csr_src, float* __restrict__ out, int N) {
    int wid = (blockIdx.x * 256 + threadIdx.x) >> 6;
    int lane = threadIdx.x & 63;
    if (wid >= N) return;
    int rs = row_start[wid];
    int d = deg_i[wid];
    float acc = 0.0f;
    int i = 0;
    for (; i + 2 <= d; i += 2) {
        int s0 = csr_src[rs + i];
        int s1 = csr_src[rs + i + 1];
        acc += z[(size_t)s0 * CPAD + lane] + z[(size_t)s1 * CPAD + lane];
    }
    if (i < d) acc += z[(size_t)csr_src[rs + i] * CPAD + lane];
    float inv = 1.0f / fmaxf((float)d, 1.0f);
    float v = -INFINITY;
    if (lane < CLASSES)
        v = acc * inv + rbuf[(size_t)wid * CPAD + lane];
    float m = v;
#pragma unroll
    for (int off = 32; off; off >>= 1) m = fmaxf(m, __shfl_xor(m, off));
    float e = (lane < CLASSES) ? expf(v - m) : 0.0f;
    float s = e;
#pragma unroll
    for (int off = 32; off; off >>= 1) s += __shfl_xor(s, off);
    if (lane < CLASSES)
        out[(size_t)wid * CLASSES + lane] = v - m - logf(s);
}

extern "C" void kernel_launch(void* const* d_in, const int* in_sizes, int n_in,
                              void* d_out, int out_size, void* d_ws, size_t ws_size,
                              hipStream_t stream) {
    const float* x   = (const float*)d_in[0];
    const int*   ei  = (const int*)d_in[1];
    const float* W1l = (const float*)d_in[2];
    const float* W1r = (const float*)d_in[3];
    const float* b1  = (const float*)d_in[4];
    const float* W2l = (const float*)d_in[5];
    const float* W2r = (const float*)d_in[6];
    const float* b2  = (const float*)d_in[7];
    float* out = (float*)d_out;

    int N = in_sizes[0] / IN_FEATS;
    int E = in_sizes[1] / 2;
    const int* src = ei;
    const int* dst = ei + E;

    // ---- ws layout ----
    // ints: [deg_i N][cursor N][blk_sums 256][row_start N][csr_src E]
    int* ws_i      = (int*)d_ws;
    int* deg_i     = ws_i;
    int* cursor    = ws_i + (size_t)N;
    int* blk_sums  = ws_i + (size_t)2 * N;
    int* row_start = ws_i + (size_t)2 * N + 256;
    int* csr_src   = ws_i + (size_t)3 * N + 256;
    size_t int_bytes = ((size_t)3 * N + 256 + (size_t)E) * sizeof(int);
    char* p = (char*)d_ws + ((int_bytes + 15) & ~(size_t)15);
    unsigned short* xbf  = (unsigned short*)p;            p += (size_t)N * 128 * 2;
    unsigned short* aggm = (unsigned short*)p;            p += (size_t)N * 128 * 2;
    unsigned short* h1   = (unsigned short*)p;            p += (size_t)N * 256 * 2;
    unsigned short* Bp1  = (unsigned short*)p;            p += 65536 * 2;
    unsigned short* Bp2  = (unsigned short*)p;            p += 24576 * 2;
    float* z    = (float*)p;                              p += (size_t)N * CPAD * 4;
    float* rbuf = (float*)p;

    hipMemsetAsync(deg_i, 0, ((size_t)2 * N + 256) * sizeof(int), stream);

    hist_kernel<<<(E + 255) / 256, 256, 0, stream>>>(dst, deg_i, E);

    int nscan = (N + SCAN_BLK - 1) / SCAN_BLK;
    scan1_kernel<<<nscan, 256, 0, stream>>>(deg_i, row_start, blk_sums, N);
    scan2_kernel<<<1, 256, 0, stream>>>(blk_sums, nscan);
    scan3_kernel<<<(N + 255) / 256, 256, 0, stream>>>(row_start, blk_sums, N);

    fill_kernel<<<(E + 255) / 256, 256, 0, stream>>>(src, dst, row_start, cursor,
                                                     csr_src, E);

    long n4 = (long)N * 128 / 4;
    xbf_kernel<<<(int)((n4 + 255) / 256), 256, 0, stream>>>(x, xbf, n4);
    prep_kernel<<<(65536 + 24576 + 255) / 256, 256, 0, stream>>>(
        W1l, W1r, W2l, W2r, Bp1, Bp2);

    {
        long long threads = (long long)N * 64;
        gather1_kernel<<<(int)((threads + 255) / 256), 256, 0, stream>>>(
            xbf, row_start, deg_i, csr_src, aggm, N);
    }
    int gblocks = (N + 63) / 64;
    mgemm1_kernel<<<gblocks, 256, 0, stream>>>(aggm, xbf, Bp1, b1, h1, N);
    mgemm2_kernel<<<gblocks, 256, 0, stream>>>(h1, Bp2, b2, z, rbuf, N);
    {
        long long threads = (long long)N * 64;
        gather2_kernel<<<(int)((threads + 255) / 256), 256, 0, stream>>>(
            z, rbuf, row_start, deg_i, csr_src, out, N);
    }
}

// Round 4
// 371.770 us; speedup vs baseline: 3.9648x; 1.2365x over previous
//
#include <hip/hip_runtime.h>
#include <math.h>

#define IN_FEATS 128
#define HIDDEN   256
#define CLASSES  41
#define CPAD     64
#define SCAN_BLK 1024
#define LDA      264   // 256 + 8 pad (bf16 elems)

typedef __attribute__((ext_vector_type(8))) short short8;
typedef __attribute__((ext_vector_type(4))) float f32x4;

__device__ __forceinline__ unsigned short f2bf(float f) {
    union { float f; unsigned u; } v; v.f = f;
    unsigned r = v.u + 0x7FFF + ((v.u >> 16) & 1);
    return (unsigned short)(r >> 16);
}
__device__ __forceinline__ float bf2f(unsigned short h) {
    union { unsigned u; float f; } v; v.u = ((unsigned)h) << 16;
    return v.f;
}

// -------- hist: rank[e] = deg_i[dst[e]]++ (atomic return = within-row rank) --
__global__ void __launch_bounds__(256)
hist_kernel(const int* __restrict__ dst, int* __restrict__ deg_i,
            int* __restrict__ rank, int E) {
    int e = blockIdx.x * blockDim.x + threadIdx.x;
    if (e < E) rank[e] = atomicAdd(&deg_i[dst[e]], 1);
}

// ---------------- 3-phase exclusive scan ------------------------------------
__global__ void __launch_bounds__(256)
scan1_kernel(const int* __restrict__ deg_i, int* __restrict__ row_start,
             int* __restrict__ blk_sums, int N) {
    __shared__ int lds[256];
    int base = blockIdx.x * SCAN_BLK;
    int t = threadIdx.x;
    int v[4];
    int s = 0;
#pragma unroll
    for (int i = 0; i < 4; ++i) {
        int idx = base + t * 4 + i;
        v[i] = (idx < N) ? deg_i[idx] : 0;
        s += v[i];
    }
    lds[t] = s;
    __syncthreads();
    for (int off = 1; off < 256; off <<= 1) {
        int val = lds[t];
        int add = (t >= off) ? lds[t - off] : 0;
        __syncthreads();
        lds[t] = val + add;
        __syncthreads();
    }
    if (t == 255) blk_sums[blockIdx.x] = lds[255];
    int run = (t == 0) ? 0 : lds[t - 1];
#pragma unroll
    for (int i = 0; i < 4; ++i) {
        int idx = base + t * 4 + i;
        if (idx < N) row_start[idx] = run;
        run += v[i];
    }
}

__global__ void __launch_bounds__(256)
scan2_kernel(int* __restrict__ blk_sums, int nb) {
    __shared__ int lds[256];
    int t = threadIdx.x;
    lds[t] = (t < nb) ? blk_sums[t] : 0;
    __syncthreads();
    for (int off = 1; off < 256; off <<= 1) {
        int val = lds[t];
        int add = (t >= off) ? lds[t - off] : 0;
        __syncthreads();
        lds[t] = val + add;
        __syncthreads();
    }
    if (t < nb) blk_sums[t] = (t == 0) ? 0 : lds[t - 1];
}

__global__ void __launch_bounds__(256)
scan3_kernel(int* __restrict__ row_start, const int* __restrict__ blk_sums, int N) {
    int idx = blockIdx.x * blockDim.x + threadIdx.x;
    if (idx < N) row_start[idx] += blk_sums[idx / SCAN_BLK];
}

// ------ fill (atomic-free): csr_src[row_start[dst[e]] + rank[e]] = src[e] ---
__global__ void __launch_bounds__(256)
fill_kernel(const int* __restrict__ src, const int* __restrict__ dst,
            const int* __restrict__ row_start, const int* __restrict__ rank,
            int* __restrict__ csr_src, int E) {
    int e = blockIdx.x * blockDim.x + threadIdx.x;
    if (e >= E) return;
    csr_src[row_start[dst[e]] + rank[e]] = src[e];
}

// ---------------- xbf: x -> bf16 --------------------------------------------
__global__ void __launch_bounds__(256)
xbf_kernel(const float* __restrict__ x, unsigned short* __restrict__ xbf, long n4) {
    long i = (long)blockIdx.x * 256 + threadIdx.x;
    if (i >= n4) return;
    float4 v = *(const float4*)(x + i * 4);
    ushort4 o;
    o.x = f2bf(v.x); o.y = f2bf(v.y); o.z = f2bf(v.z); o.w = f2bf(v.w);
    *(ushort4*)(xbf + i * 4) = o;
}

// ------- prep: pack [W1l;W1r] -> Bp1 (256x256) and [W2l|W2r] -> Bp2 (256x96) -
__global__ void __launch_bounds__(256)
prep_kernel(const float* __restrict__ W1l, const float* __restrict__ W1r,
            const float* __restrict__ W2l, const float* __restrict__ W2r,
            unsigned short* __restrict__ Bp1, unsigned short* __restrict__ Bp2) {
    int idx = blockIdx.x * 256 + threadIdx.x;
    if (idx < 256 * 256) {
        int k = idx >> 8, c = idx & 255;
        float v = (k < 128) ? W1l[k * 256 + c] : W1r[(k - 128) * 256 + c];
        Bp1[((k >> 5) * 256 + c) * 32 + ((k & 31) >> 3) * 8 + (k & 7)] = f2bf(v);
    } else {
        int j = idx - 65536;
        if (j < 256 * 96) {
            int k = j / 96, c = j % 96;
            float v = 0.0f;
            if (c < 41) v = W2l[k * 41 + c];
            else if (c >= 48 && c < 89) v = W2r[k * 41 + (c - 48)];
            Bp2[((k >> 5) * 96 + c) * 32 + ((k & 31) >> 3) * 8 + (k & 7)] = f2bf(v);
        }
    }
}

// ---------------- gather1: aggm_bf[n] = bf16(mean_{s} xbf[s]) ---------------
__global__ void __launch_bounds__(256)
gather1_kernel(const unsigned short* __restrict__ xbf,
               const int* __restrict__ row_start, const int* __restrict__ deg_i,
               const int* __restrict__ csr_src, unsigned short* __restrict__ aggm,
               int N) {
    int wid = (blockIdx.x * 256 + threadIdx.x) >> 6;
    int lane = threadIdx.x & 63;
    if (wid >= N) return;
    int rs = row_start[wid];
    int d = deg_i[wid];
    const unsigned* xp = (const unsigned*)xbf;
    float ax = 0.0f, ay = 0.0f;
    int i = 0;
    for (; i + 2 <= d; i += 2) {
        int s0 = csr_src[rs + i];
        int s1 = csr_src[rs + i + 1];
        unsigned u0 = xp[(size_t)s0 * 64 + lane];
        unsigned u1 = xp[(size_t)s1 * 64 + lane];
        ax += bf2f((unsigned short)(u0 & 0xffff)) + bf2f((unsigned short)(u1 & 0xffff));
        ay += bf2f((unsigned short)(u0 >> 16))    + bf2f((unsigned short)(u1 >> 16));
    }
    if (i < d) {
        unsigned u0 = xp[(size_t)csr_src[rs + i] * 64 + lane];
        ax += bf2f((unsigned short)(u0 & 0xffff));
        ay += bf2f((unsigned short)(u0 >> 16));
    }
    float inv = 1.0f / fmaxf((float)d, 1.0f);
    unsigned out = ((unsigned)f2bf(ay * inv) << 16) | (unsigned)f2bf(ax * inv);
    ((unsigned*)aggm)[(size_t)wid * 64 + lane] = out;
}

// ------- mgemm1: h1 = bf16(relu([aggm|xbf] @ Bp1 + b1)), MFMA ---------------
__global__ void __launch_bounds__(256)
mgemm1_kernel(const unsigned short* __restrict__ aggm,
              const unsigned short* __restrict__ xbf,
              const unsigned short* __restrict__ Bp1, const float* __restrict__ b1,
              unsigned short* __restrict__ h1, int N) {
    __shared__ __align__(16) unsigned short alds[64 * LDA];
    int n0 = blockIdx.x * 64;
    int t = threadIdx.x;
#pragma unroll
    for (int i = 0; i < 8; ++i) {
        int cid = t + i * 256;
        int row = cid >> 5, c16 = cid & 31;
        int gr = n0 + row;
        uint4 v = make_uint4(0, 0, 0, 0);
        if (gr < N) {
            const unsigned short* srcp = (c16 < 16)
                ? (aggm + (size_t)gr * 128 + c16 * 8)
                : (xbf  + (size_t)gr * 128 + (c16 - 16) * 8);
            v = *(const uint4*)srcp;
        }
        *(uint4*)&alds[row * LDA + c16 * 8] = v;
    }
    __syncthreads();
    int wid = t >> 6, lane = t & 63;
    int l15 = lane & 15, g = lane >> 4;
    int col0 = wid * 64;
    f32x4 acc[4][4];
#pragma unroll
    for (int mf = 0; mf < 4; ++mf)
#pragma unroll
        for (int nf = 0; nf < 4; ++nf) acc[mf][nf] = (f32x4)(0.0f);
    for (int ks = 0; ks < 8; ++ks) {
        short8 af[4], bfr[4];
#pragma unroll
        for (int mf = 0; mf < 4; ++mf)
            af[mf] = *(const short8*)&alds[(mf * 16 + l15) * LDA + ks * 32 + g * 8];
#pragma unroll
        for (int nf = 0; nf < 4; ++nf)
            bfr[nf] = *(const short8*)&Bp1[((size_t)ks * 256 + col0 + nf * 16 + l15) * 32 + g * 8];
#pragma unroll
        for (int mf = 0; mf < 4; ++mf)
#pragma unroll
            for (int nf = 0; nf < 4; ++nf)
                acc[mf][nf] = __builtin_amdgcn_mfma_f32_16x16x32_bf16(
                    af[mf], bfr[nf], acc[mf][nf], 0, 0, 0);
    }
    float bc[4];
#pragma unroll
    for (int nf = 0; nf < 4; ++nf) bc[nf] = b1[col0 + nf * 16 + l15];
#pragma unroll
    for (int mf = 0; mf < 4; ++mf) {
        int rowb = n0 + mf * 16 + g * 4;
#pragma unroll
        for (int r = 0; r < 4; ++r) {
            int row = rowb + r;
            if (row < N) {
#pragma unroll
                for (int nf = 0; nf < 4; ++nf)
                    h1[(size_t)row * 256 + col0 + nf * 16 + l15] =
                        f2bf(fmaxf(acc[mf][nf][r] + bc[nf], 0.0f));
            }
        }
    }
}

// ------- mgemm2: zb = bf16(h1@W2l) ; rbuf = h1@W2r + b2 ---------------------
__global__ void __launch_bounds__(256)
mgemm2_kernel(const unsigned short* __restrict__ h1,
              const unsigned short* __restrict__ Bp2, const float* __restrict__ b2,
              unsigned short* __restrict__ zb, float* __restrict__ rbuf, int N) {
    __shared__ __align__(16) unsigned short alds[64 * LDA];
    int n0 = blockIdx.x * 64;
    int t = threadIdx.x;
#pragma unroll
    for (int i = 0; i < 8; ++i) {
        int cid = t + i * 256;
        int row = cid >> 5, c16 = cid & 31;
        int gr = n0 + row;
        uint4 v = make_uint4(0, 0, 0, 0);
        if (gr < N) v = *(const uint4*)(h1 + (size_t)gr * 256 + c16 * 8);
        *(uint4*)&alds[row * LDA + c16 * 8] = v;
    }
    __syncthreads();
    int wid = t >> 6, lane = t & 63;
    int l15 = lane & 15, g = lane >> 4;
    int wr = wid >> 1, wc = wid & 1;
    f32x4 acc[2][3];
#pragma unroll
    for (int mf = 0; mf < 2; ++mf)
#pragma unroll
        for (int nf = 0; nf < 3; ++nf) acc[mf][nf] = (f32x4)(0.0f);
    for (int ks = 0; ks < 8; ++ks) {
        short8 af[2], bfr[3];
#pragma unroll
        for (int mf = 0; mf < 2; ++mf)
            af[mf] = *(const short8*)&alds[(wr * 32 + mf * 16 + l15) * LDA + ks * 32 + g * 8];
#pragma unroll
        for (int nf = 0; nf < 3; ++nf)
            bfr[nf] = *(const short8*)&Bp2[((size_t)ks * 96 + wc * 48 + nf * 16 + l15) * 32 + g * 8];
#pragma unroll
        for (int mf = 0; mf < 2; ++mf)
#pragma unroll
            for (int nf = 0; nf < 3; ++nf)
                acc[mf][nf] = __builtin_amdgcn_mfma_f32_16x16x32_bf16(
                    af[mf], bfr[nf], acc[mf][nf], 0, 0, 0);
    }
#pragma unroll
    for (int nf = 0; nf < 3; ++nf) {
        int col = wc * 48 + nf * 16 + l15;
        float bb = (col >= 48 && col < 89) ? b2[col - 48] : 0.0f;
#pragma unroll
        for (int mf = 0; mf < 2; ++mf) {
            int rowb = n0 + wr * 32 + mf * 16 + g * 4;
#pragma unroll
            for (int r = 0; r < 4; ++r) {
                int row = rowb + r;
                if (row < N) {
                    float v = acc[mf][nf][r];
                    if (col < 41)                   zb[(size_t)row * CPAD + col] = f2bf(v);
                    else if (col >= 48 && col < 89) rbuf[(size_t)row * CPAD + (col - 48)] = v + bb;
                }
            }
        }
    }
}

// -------- gather2+final: out = log_softmax(mean_{s}(zb[s]) + rbuf) ----------
__global__ void __launch_bounds__(256)
gather2_kernel(const unsigned short* __restrict__ zb, const float* __restrict__ rbuf,
               const int* __restrict__ row_start, const int* __restrict__ deg_i,
               const int* __restrict__ csr_src, float* __restrict__ out, int N) {
    int wid = (blockIdx.x * 256 + threadIdx.x) >> 6;
    int lane = threadIdx.x & 63;
    if (wid >= N) return;
    int rs = row_start[wid];
    int d = deg_i[wid];
    float acc = 0.0f;
    int i = 0;
    for (; i + 2 <= d; i += 2) {
        int s0 = csr_src[rs + i];
        int s1 = csr_src[rs + i + 1];
        acc += bf2f(zb[(size_t)s0 * CPAD + lane]) + bf2f(zb[(size_t)s1 * CPAD + lane]);
    }
    if (i < d) acc += bf2f(zb[(size_t)csr_src[rs + i] * CPAD + lane]);
    float inv = 1.0f / fmaxf((float)d, 1.0f);
    float v = -INFINITY;
    if (lane < CLASSES)
        v = acc * inv + rbuf[(size_t)wid * CPAD + lane];
    float m = v;
#pragma unroll
    for (int off = 32; off; off >>= 1) m = fmaxf(m, __shfl_xor(m, off));
    float e = (lane < CLASSES) ? expf(v - m) : 0.0f;
    float s = e;
#pragma unroll
    for (int off = 32; off; off >>= 1) s += __shfl_xor(s, off);
    if (lane < CLASSES)
        out[(size_t)wid * CLASSES + lane] = v - m - logf(s);
}

extern "C" void kernel_launch(void* const* d_in, const int* in_sizes, int n_in,
                              void* d_out, int out_size, void* d_ws, size_t ws_size,
                              hipStream_t stream) {
    const float* x   = (const float*)d_in[0];
    const int*   ei  = (const int*)d_in[1];
    const float* W1l = (const float*)d_in[2];
    const float* W1r = (const float*)d_in[3];
    const float* b1  = (const float*)d_in[4];
    const float* W2l = (const float*)d_in[5];
    const float* W2r = (const float*)d_in[6];
    const float* b2  = (const float*)d_in[7];
    float* out = (float*)d_out;

    int N = in_sizes[0] / IN_FEATS;
    int E = in_sizes[1] / 2;
    const int* src = ei;
    const int* dst = ei + E;

    // ints: [deg_i N][blk_sums 256][row_start N][rank E][csr_src E]
    int* ws_i      = (int*)d_ws;
    int* deg_i     = ws_i;
    int* blk_sums  = ws_i + (size_t)N;
    int* row_start = ws_i + (size_t)N + 256;
    int* rank      = ws_i + (size_t)2 * N + 256;
    int* csr_src   = rank + (size_t)E;
    size_t int_bytes = ((size_t)2 * N + 256 + 2 * (size_t)E) * sizeof(int);
    char* p = (char*)d_ws + ((int_bytes + 15) & ~(size_t)15);
    unsigned short* xbf  = (unsigned short*)p;            p += (size_t)N * 128 * 2;
    unsigned short* aggm = (unsigned short*)p;            p += (size_t)N * 128 * 2;
    unsigned short* h1   = (unsigned short*)p;            p += (size_t)N * 256 * 2;
    unsigned short* Bp1  = (unsigned short*)p;            p += 65536 * 2;
    unsigned short* Bp2  = (unsigned short*)p;            p += 24576 * 2;
    unsigned short* zb   = (unsigned short*)p;            p += (size_t)N * CPAD * 2;
    float* rbuf = (float*)p;

    hipMemsetAsync(deg_i, 0, ((size_t)N + 256) * sizeof(int), stream);

    hist_kernel<<<(E + 255) / 256, 256, 0, stream>>>(dst, deg_i, rank, E);

    int nscan = (N + SCAN_BLK - 1) / SCAN_BLK;
    scan1_kernel<<<nscan, 256, 0, stream>>>(deg_i, row_start, blk_sums, N);
    scan2_kernel<<<1, 256, 0, stream>>>(blk_sums, nscan);
    scan3_kernel<<<(N + 255) / 256, 256, 0, stream>>>(row_start, blk_sums, N);

    fill_kernel<<<(E + 255) / 256, 256, 0, stream>>>(src, dst, row_start, rank,
                                                     csr_src, E);

    long n4 = (long)N * 128 / 4;
    xbf_kernel<<<(int)((n4 + 255) / 256), 256, 0, stream>>>(x, xbf, n4);
    prep_kernel<<<(65536 + 24576 + 255) / 256, 256, 0, stream>>>(
        W1l, W1r, W2l, W2r, Bp1, Bp2);

    {
        long long threads = (long long)N * 64;
        gather1_kernel<<<(int)((threads + 255) / 256), 256, 0, stream>>>(
            xbf, row_start, deg_i, csr_src, aggm, N);
    }
    int gblocks = (N + 63) / 64;
    mgemm1_kernel<<<gblocks, 256, 0, stream>>>(aggm, xbf, Bp1, b1, h1, N);
    mgemm2_kernel<<<gblocks, 256, 0, stream>>>(h1, Bp2, b2, zb, rbuf, N);
    {
        long long threads = (long long)N * 64;
        gather2_kernel<<<(int)((threads + 255) / 256), 256, 0, stream>>>(
            zb, rbuf, row_start, deg_i, csr_src, out, N);
    }
}

// Round 5
// 301.289 us; speedup vs baseline: 4.8922x; 1.2339x over previous
//
#include <hip/hip_runtime.h>
#include <math.h>

#define IN_FEATS 128
#define HIDDEN   256
#define CLASSES  41
#define CPAD     64
#define SCAN_BLK 1024
#define LDA      264   // 256 + 8 pad (bf16 elems)

typedef __attribute__((ext_vector_type(8))) short short8;
typedef __attribute__((ext_vector_type(4))) float f32x4;

__device__ __forceinline__ unsigned short f2bf(float f) {
    union { float f; unsigned u; } v; v.f = f;
    unsigned r = v.u + 0x7FFF + ((v.u >> 16) & 1);
    return (unsigned short)(r >> 16);
}
__device__ __forceinline__ float bf2f(unsigned short h) {
    union { unsigned u; float f; } v; v.u = ((unsigned)h) << 16;
    return v.f;
}

// -------- hist: rank[e] = deg_i[dst[e]]++ (atomic return = within-row rank) --
__global__ void __launch_bounds__(256)
hist_kernel(const int* __restrict__ dst, int* __restrict__ deg_i,
            int* __restrict__ rank, int E) {
    int e = blockIdx.x * blockDim.x + threadIdx.x;
    if (e < E) rank[e] = atomicAdd(&deg_i[dst[e]], 1);
}

// ---------------- 3-phase exclusive scan ------------------------------------
__global__ void __launch_bounds__(256)
scan1_kernel(const int* __restrict__ deg_i, int* __restrict__ row_start,
             int* __restrict__ blk_sums, int N) {
    __shared__ int lds[256];
    int base = blockIdx.x * SCAN_BLK;
    int t = threadIdx.x;
    int v[4];
    int s = 0;
#pragma unroll
    for (int i = 0; i < 4; ++i) {
        int idx = base + t * 4 + i;
        v[i] = (idx < N) ? deg_i[idx] : 0;
        s += v[i];
    }
    lds[t] = s;
    __syncthreads();
    for (int off = 1; off < 256; off <<= 1) {
        int val = lds[t];
        int add = (t >= off) ? lds[t - off] : 0;
        __syncthreads();
        lds[t] = val + add;
        __syncthreads();
    }
    if (t == 255) blk_sums[blockIdx.x] = lds[255];
    int run = (t == 0) ? 0 : lds[t - 1];
#pragma unroll
    for (int i = 0; i < 4; ++i) {
        int idx = base + t * 4 + i;
        if (idx < N) row_start[idx] = run;
        run += v[i];
    }
}

__global__ void __launch_bounds__(256)
scan2_kernel(int* __restrict__ blk_sums, int nb) {
    __shared__ int lds[256];
    int t = threadIdx.x;
    lds[t] = (t < nb) ? blk_sums[t] : 0;
    __syncthreads();
    for (int off = 1; off < 256; off <<= 1) {
        int val = lds[t];
        int add = (t >= off) ? lds[t - off] : 0;
        __syncthreads();
        lds[t] = val + add;
        __syncthreads();
    }
    if (t < nb) blk_sums[t] = (t == 0) ? 0 : lds[t - 1];
}

__global__ void __launch_bounds__(256)
scan3_kernel(int* __restrict__ row_start, const int* __restrict__ blk_sums, int N) {
    int idx = blockIdx.x * blockDim.x + threadIdx.x;
    if (idx < N) row_start[idx] += blk_sums[idx / SCAN_BLK];
}

// ------ fill (atomic-free): csr_src[row_start[dst[e]] + rank[e]] = src[e] ---
__global__ void __launch_bounds__(256)
fill_kernel(const int* __restrict__ src, const int* __restrict__ dst,
            const int* __restrict__ row_start, const int* __restrict__ rank,
            int* __restrict__ csr_src, int E) {
    int e = blockIdx.x * blockDim.x + threadIdx.x;
    if (e >= E) return;
    csr_src[row_start[dst[e]] + rank[e]] = src[e];
}

// ---------------- xbf: x -> bf16 --------------------------------------------
__global__ void __launch_bounds__(256)
xbf_kernel(const float* __restrict__ x, unsigned short* __restrict__ xbf, long n4) {
    long i = (long)blockIdx.x * 256 + threadIdx.x;
    if (i >= n4) return;
    float4 v = *(const float4*)(x + i * 4);
    ushort4 o;
    o.x = f2bf(v.x); o.y = f2bf(v.y); o.z = f2bf(v.z); o.w = f2bf(v.w);
    *(ushort4*)(xbf + i * 4) = o;
}

// ------- prep: pack [W1l;W1r] -> Bp1 (256x256) and [W2l|W2r] -> Bp2 (256x96) -
__global__ void __launch_bounds__(256)
prep_kernel(const float* __restrict__ W1l, const float* __restrict__ W1r,
            const float* __restrict__ W2l, const float* __restrict__ W2r,
            unsigned short* __restrict__ Bp1, unsigned short* __restrict__ Bp2) {
    int idx = blockIdx.x * 256 + threadIdx.x;
    if (idx < 256 * 256) {
        int k = idx >> 8, c = idx & 255;
        float v = (k < 128) ? W1l[k * 256 + c] : W1r[(k - 128) * 256 + c];
        Bp1[((k >> 5) * 256 + c) * 32 + ((k & 31) >> 3) * 8 + (k & 7)] = f2bf(v);
    } else {
        int j = idx - 65536;
        if (j < 256 * 96) {
            int k = j / 96, c = j % 96;
            float v = 0.0f;
            if (c < 41) v = W2l[k * 41 + c];
            else if (c >= 48 && c < 89) v = W2r[k * 41 + (c - 48)];
            Bp2[((k >> 5) * 96 + c) * 32 + ((k & 31) >> 3) * 8 + (k & 7)] = f2bf(v);
        }
    }
}

// ------- gather1: aggm_bf[n] = bf16(mean_{s} xbf[s]), unroll-4 MLP ----------
__global__ void __launch_bounds__(256)
gather1_kernel(const unsigned short* __restrict__ xbf,
               const int* __restrict__ row_start, const int* __restrict__ deg_i,
               const int* __restrict__ csr_src, unsigned short* __restrict__ aggm,
               int N) {
    int wid = (blockIdx.x * 256 + threadIdx.x) >> 6;
    int lane = threadIdx.x & 63;
    if (wid >= N) return;
    int rs = row_start[wid];
    int d = deg_i[wid];
    const unsigned* xp = (const unsigned*)xbf;
    float a0 = 0.f, a1 = 0.f, b0 = 0.f, b1 = 0.f;
    float c0 = 0.f, c1 = 0.f, e0 = 0.f, e1 = 0.f;
    int i = 0;
    for (; i + 4 <= d; i += 4) {
        int s0 = csr_src[rs + i + 0];
        int s1 = csr_src[rs + i + 1];
        int s2 = csr_src[rs + i + 2];
        int s3 = csr_src[rs + i + 3];
        unsigned u0 = xp[(size_t)s0 * 64 + lane];
        unsigned u1 = xp[(size_t)s1 * 64 + lane];
        unsigned u2 = xp[(size_t)s2 * 64 + lane];
        unsigned u3 = xp[(size_t)s3 * 64 + lane];
        a0 += bf2f((unsigned short)u0); a1 += bf2f((unsigned short)(u0 >> 16));
        b0 += bf2f((unsigned short)u1); b1 += bf2f((unsigned short)(u1 >> 16));
        c0 += bf2f((unsigned short)u2); c1 += bf2f((unsigned short)(u2 >> 16));
        e0 += bf2f((unsigned short)u3); e1 += bf2f((unsigned short)(u3 >> 16));
    }
    for (; i < d; ++i) {
        unsigned u0 = xp[(size_t)csr_src[rs + i] * 64 + lane];
        a0 += bf2f((unsigned short)u0); a1 += bf2f((unsigned short)(u0 >> 16));
    }
    float ax = (a0 + b0) + (c0 + e0);
    float ay = (a1 + b1) + (c1 + e1);
    float inv = 1.0f / fmaxf((float)d, 1.0f);
    unsigned o = ((unsigned)f2bf(ay * inv) << 16) | (unsigned)f2bf(ax * inv);
    ((unsigned*)aggm)[(size_t)wid * 64 + lane] = o;
}

// ------- mgemm1: h1 = bf16(relu([aggm|xbf] @ Bp1 + b1)), MFMA ---------------
__global__ void __launch_bounds__(256)
mgemm1_kernel(const unsigned short* __restrict__ aggm,
              const unsigned short* __restrict__ xbf,
              const unsigned short* __restrict__ Bp1, const float* __restrict__ b1,
              unsigned short* __restrict__ h1, int N) {
    __shared__ __align__(16) unsigned short alds[64 * LDA];
    int n0 = blockIdx.x * 64;
    int t = threadIdx.x;
#pragma unroll
    for (int i = 0; i < 8; ++i) {
        int cid = t + i * 256;
        int row = cid >> 5, c16 = cid & 31;
        int gr = n0 + row;
        uint4 v = make_uint4(0, 0, 0, 0);
        if (gr < N) {
            const unsigned short* srcp = (c16 < 16)
                ? (aggm + (size_t)gr * 128 + c16 * 8)
                : (xbf  + (size_t)gr * 128 + (c16 - 16) * 8);
            v = *(const uint4*)srcp;
        }
        *(uint4*)&alds[row * LDA + c16 * 8] = v;
    }
    __syncthreads();
    int wid = t >> 6, lane = t & 63;
    int l15 = lane & 15, g = lane >> 4;
    int col0 = wid * 64;
    f32x4 acc[4][4];
#pragma unroll
    for (int mf = 0; mf < 4; ++mf)
#pragma unroll
        for (int nf = 0; nf < 4; ++nf) acc[mf][nf] = (f32x4)(0.0f);
    for (int ks = 0; ks < 8; ++ks) {
        short8 af[4], bfr[4];
#pragma unroll
        for (int mf = 0; mf < 4; ++mf)
            af[mf] = *(const short8*)&alds[(mf * 16 + l15) * LDA + ks * 32 + g * 8];
#pragma unroll
        for (int nf = 0; nf < 4; ++nf)
            bfr[nf] = *(const short8*)&Bp1[((size_t)ks * 256 + col0 + nf * 16 + l15) * 32 + g * 8];
#pragma unroll
        for (int mf = 0; mf < 4; ++mf)
#pragma unroll
            for (int nf = 0; nf < 4; ++nf)
                acc[mf][nf] = __builtin_amdgcn_mfma_f32_16x16x32_bf16(
                    af[mf], bfr[nf], acc[mf][nf], 0, 0, 0);
    }
    float bc[4];
#pragma unroll
    for (int nf = 0; nf < 4; ++nf) bc[nf] = b1[col0 + nf * 16 + l15];
#pragma unroll
    for (int mf = 0; mf < 4; ++mf) {
        int rowb = n0 + mf * 16 + g * 4;
#pragma unroll
        for (int r = 0; r < 4; ++r) {
            int row = rowb + r;
            if (row < N) {
#pragma unroll
                for (int nf = 0; nf < 4; ++nf)
                    h1[(size_t)row * 256 + col0 + nf * 16 + l15] =
                        f2bf(fmaxf(acc[mf][nf][r] + bc[nf], 0.0f));
            }
        }
    }
}

// ------- mgemm2: zb = bf16(h1@W2l) ; rbuf = h1@W2r + b2 ---------------------
__global__ void __launch_bounds__(256)
mgemm2_kernel(const unsigned short* __restrict__ h1,
              const unsigned short* __restrict__ Bp2, const float* __restrict__ b2,
              unsigned short* __restrict__ zb, float* __restrict__ rbuf, int N) {
    __shared__ __align__(16) unsigned short alds[64 * LDA];
    int n0 = blockIdx.x * 64;
    int t = threadIdx.x;
#pragma unroll
    for (int i = 0; i < 8; ++i) {
        int cid = t + i * 256;
        int row = cid >> 5, c16 = cid & 31;
        int gr = n0 + row;
        uint4 v = make_uint4(0, 0, 0, 0);
        if (gr < N) v = *(const uint4*)(h1 + (size_t)gr * 256 + c16 * 8);
        *(uint4*)&alds[row * LDA + c16 * 8] = v;
    }
    __syncthreads();
    int wid = t >> 6, lane = t & 63;
    int l15 = lane & 15, g = lane >> 4;
    int wr = wid >> 1, wc = wid & 1;
    f32x4 acc[2][3];
#pragma unroll
    for (int mf = 0; mf < 2; ++mf)
#pragma unroll
        for (int nf = 0; nf < 3; ++nf) acc[mf][nf] = (f32x4)(0.0f);
    for (int ks = 0; ks < 8; ++ks) {
        short8 af[2], bfr[3];
#pragma unroll
        for (int mf = 0; mf < 2; ++mf)
            af[mf] = *(const short8*)&alds[(wr * 32 + mf * 16 + l15) * LDA + ks * 32 + g * 8];
#pragma unroll
        for (int nf = 0; nf < 3; ++nf)
            bfr[nf] = *(const short8*)&Bp2[((size_t)ks * 96 + wc * 48 + nf * 16 + l15) * 32 + g * 8];
#pragma unroll
        for (int mf = 0; mf < 2; ++mf)
#pragma unroll
            for (int nf = 0; nf < 3; ++nf)
                acc[mf][nf] = __builtin_amdgcn_mfma_f32_16x16x32_bf16(
                    af[mf], bfr[nf], acc[mf][nf], 0, 0, 0);
    }
#pragma unroll
    for (int nf = 0; nf < 3; ++nf) {
        int col = wc * 48 + nf * 16 + l15;
        float bb = (col >= 48 && col < 89) ? b2[col - 48] : 0.0f;
#pragma unroll
        for (int mf = 0; mf < 2; ++mf) {
            int rowb = n0 + wr * 32 + mf * 16 + g * 4;
#pragma unroll
            for (int r = 0; r < 4; ++r) {
                int row = rowb + r;
                if (row < N) {
                    float v = acc[mf][nf][r];
                    if (col < 41)                   zb[(size_t)row * CPAD + col] = f2bf(v);
                    else if (col >= 48 && col < 89) rbuf[(size_t)row * CPAD + (col - 48)] = v + bb;
                }
            }
        }
    }
}

// -- gather2+final: 2 nodes/wave (32 lanes each, u32=2 classes/lane), unroll-4
__global__ void __launch_bounds__(256)
gather2_kernel(const unsigned* __restrict__ zb32, const float* __restrict__ rbuf,
               const int* __restrict__ row_start, const int* __restrict__ deg_i,
               const int* __restrict__ csr_src, float* __restrict__ out, int N) {
    int nid = (blockIdx.x * 256 + threadIdx.x) >> 5;
    int l = threadIdx.x & 31;
    if (nid >= N) return;
    int rs = row_start[nid];
    int d = deg_i[nid];
    float a0 = 0.f, a1 = 0.f, b0 = 0.f, b1 = 0.f;
    float c0f = 0.f, c1f = 0.f, e0f = 0.f, e1f = 0.f;
    int i = 0;
    for (; i + 4 <= d; i += 4) {
        int s0 = csr_src[rs + i + 0];
        int s1 = csr_src[rs + i + 1];
        int s2 = csr_src[rs + i + 2];
        int s3 = csr_src[rs + i + 3];
        unsigned u0 = zb32[(size_t)s0 * 32 + l];
        unsigned u1 = zb32[(size_t)s1 * 32 + l];
        unsigned u2 = zb32[(size_t)s2 * 32 + l];
        unsigned u3 = zb32[(size_t)s3 * 32 + l];
        a0  += bf2f((unsigned short)u0); a1  += bf2f((unsigned short)(u0 >> 16));
        b0  += bf2f((unsigned short)u1); b1  += bf2f((unsigned short)(u1 >> 16));
        c0f += bf2f((unsigned short)u2); c1f += bf2f((unsigned short)(u2 >> 16));
        e0f += bf2f((unsigned short)u3); e1f += bf2f((unsigned short)(u3 >> 16));
    }
    for (; i < d; ++i) {
        unsigned u0 = zb32[(size_t)csr_src[rs + i] * 32 + l];
        a0 += bf2f((unsigned short)u0); a1 += bf2f((unsigned short)(u0 >> 16));
    }
    float inv = 1.0f / fmaxf((float)d, 1.0f);
    int col0 = 2 * l, col1 = 2 * l + 1;
    float2 rb = *(const float2*)&rbuf[(size_t)nid * CPAD + 2 * l];
    float v0 = (col0 < CLASSES) ? ((a0 + b0) + (c0f + e0f)) * inv + rb.x : -INFINITY;
    float v1 = (col1 < CLASSES) ? ((a1 + b1) + (c1f + e1f)) * inv + rb.y : -INFINITY;
    float m = fmaxf(v0, v1);
#pragma unroll
    for (int off = 16; off; off >>= 1) m = fmaxf(m, __shfl_xor(m, off, 32));
    float ex0 = (col0 < CLASSES) ? expf(v0 - m) : 0.0f;
    float ex1 = (col1 < CLASSES) ? expf(v1 - m) : 0.0f;
    float s = ex0 + ex1;
#pragma unroll
    for (int off = 16; off; off >>= 1) s += __shfl_xor(s, off, 32);
    float lse = m + logf(s);
    if (col0 < CLASSES) out[(size_t)nid * CLASSES + col0] = v0 - lse;
    if (col1 < CLASSES) out[(size_t)nid * CLASSES + col1] = v1 - lse;
}

extern "C" void kernel_launch(void* const* d_in, const int* in_sizes, int n_in,
                              void* d_out, int out_size, void* d_ws, size_t ws_size,
                              hipStream_t stream) {
    const float* x   = (const float*)d_in[0];
    const int*   ei  = (const int*)d_in[1];
    const float* W1l = (const float*)d_in[2];
    const float* W1r = (const float*)d_in[3];
    const float* b1  = (const float*)d_in[4];
    const float* W2l = (const float*)d_in[5];
    const float* W2r = (const float*)d_in[6];
    const float* b2  = (const float*)d_in[7];
    float* out = (float*)d_out;

    int N = in_sizes[0] / IN_FEATS;
    int E = in_sizes[1] / 2;
    const int* src = ei;
    const int* dst = ei + E;

    // ints: [deg_i N][blk_sums 256][row_start N][rank E][csr_src E]
    int* ws_i      = (int*)d_ws;
    int* deg_i     = ws_i;
    int* blk_sums  = ws_i + (size_t)N;
    int* row_start = ws_i + (size_t)N + 256;
    int* rank      = ws_i + (size_t)2 * N + 256;
    int* csr_src   = rank + (size_t)E;
    size_t int_bytes = ((size_t)2 * N + 256 + 2 * (size_t)E) * sizeof(int);
    char* p = (char*)d_ws + ((int_bytes + 15) & ~(size_t)15);
    unsigned short* xbf  = (unsigned short*)p;            p += (size_t)N * 128 * 2;
    unsigned short* aggm = (unsigned short*)p;            p += (size_t)N * 128 * 2;
    unsigned short* h1   = (unsigned short*)p;            p += (size_t)N * 256 * 2;
    unsigned short* Bp1  = (unsigned short*)p;            p += 65536 * 2;
    unsigned short* Bp2  = (unsigned short*)p;            p += 24576 * 2;
    unsigned short* zb   = (unsigned short*)p;            p += (size_t)N * CPAD * 2;
    float* rbuf = (float*)p;

    hipMemsetAsync(deg_i, 0, ((size_t)N + 256) * sizeof(int), stream);

    hist_kernel<<<(E + 255) / 256, 256, 0, stream>>>(dst, deg_i, rank, E);

    int nscan = (N + SCAN_BLK - 1) / SCAN_BLK;
    scan1_kernel<<<nscan, 256, 0, stream>>>(deg_i, row_start, blk_sums, N);
    scan2_kernel<<<1, 256, 0, stream>>>(blk_sums, nscan);
    scan3_kernel<<<(N + 255) / 256, 256, 0, stream>>>(row_start, blk_sums, N);

    fill_kernel<<<(E + 255) / 256, 256, 0, stream>>>(src, dst, row_start, rank,
                                                     csr_src, E);

    long n4 = (long)N * 128 / 4;
    xbf_kernel<<<(int)((n4 + 255) / 256), 256, 0, stream>>>(x, xbf, n4);
    prep_kernel<<<(65536 + 24576 + 255) / 256, 256, 0, stream>>>(
        W1l, W1r, W2l, W2r, Bp1, Bp2);

    {
        long long threads = (long long)N * 64;
        gather1_kernel<<<(int)((threads + 255) / 256), 256, 0, stream>>>(
            xbf, row_start, deg_i, csr_src, aggm, N);
    }
    int gblocks = (N + 63) / 64;
    mgemm1_kernel<<<gblocks, 256, 0, stream>>>(aggm, xbf, Bp1, b1, h1, N);
    mgemm2_kernel<<<gblocks, 256, 0, stream>>>(h1, Bp2, b2, zb, rbuf, N);
    {
        long long threads = (long long)N * 32;
        gather2_kernel<<<(int)((threads + 255) / 256), 256, 0, stream>>>(
            (const unsigned*)zb, rbuf, row_start, deg_i, csr_src, out, N);
    }
}

// Round 6
// 284.484 us; speedup vs baseline: 5.1812x; 1.0591x over previous
//
#include <hip/hip_runtime.h>
#include <math.h>

#define IN_FEATS 128
#define HIDDEN   256
#define CLASSES  41
#define CPAD     64
#define SCAN_BLK 1024
#define LDA      264   // 256 + 8 pad (bf16 elems)

typedef __attribute__((ext_vector_type(8))) short short8;
typedef __attribute__((ext_vector_type(4))) float f32x4;

__device__ __forceinline__ unsigned short f2bf(float f) {
    union { float f; unsigned u; } v; v.f = f;
    unsigned r = v.u + 0x7FFF + ((v.u >> 16) & 1);
    return (unsigned short)(r >> 16);
}
__device__ __forceinline__ float bf2f(unsigned short h) {
    union { unsigned u; float f; } v; v.u = ((unsigned)h) << 16;
    return v.f;
}

// -------- hist: rank[e] = deg_i[dst[e]]++ (atomic return = within-row rank) --
__global__ void __launch_bounds__(256)
hist_kernel(const int* __restrict__ dst, int* __restrict__ deg_i,
            unsigned short* __restrict__ rank, int E) {
    int e = blockIdx.x * blockDim.x + threadIdx.x;
    if (e < E) rank[e] = (unsigned short)atomicAdd(&deg_i[dst[e]], 1);
}

// ---------------- 3-phase exclusive scan ------------------------------------
__global__ void __launch_bounds__(256)
scan1_kernel(const int* __restrict__ deg_i, int* __restrict__ row_start,
             int* __restrict__ blk_sums, int N) {
    __shared__ int lds[256];
    int base = blockIdx.x * SCAN_BLK;
    int t = threadIdx.x;
    int v[4];
    int s = 0;
#pragma unroll
    for (int i = 0; i < 4; ++i) {
        int idx = base + t * 4 + i;
        v[i] = (idx < N) ? deg_i[idx] : 0;
        s += v[i];
    }
    lds[t] = s;
    __syncthreads();
    for (int off = 1; off < 256; off <<= 1) {
        int val = lds[t];
        int add = (t >= off) ? lds[t - off] : 0;
        __syncthreads();
        lds[t] = val + add;
        __syncthreads();
    }
    if (t == 255) blk_sums[blockIdx.x] = lds[255];
    int run = (t == 0) ? 0 : lds[t - 1];
#pragma unroll
    for (int i = 0; i < 4; ++i) {
        int idx = base + t * 4 + i;
        if (idx < N) row_start[idx] = run;
        run += v[i];
    }
}

__global__ void __launch_bounds__(256)
scan2_kernel(int* __restrict__ blk_sums, int nb) {
    __shared__ int lds[256];
    int t = threadIdx.x;
    lds[t] = (t < nb) ? blk_sums[t] : 0;
    __syncthreads();
    for (int off = 1; off < 256; off <<= 1) {
        int val = lds[t];
        int add = (t >= off) ? lds[t - off] : 0;
        __syncthreads();
        lds[t] = val + add;
        __syncthreads();
    }
    if (t < nb) blk_sums[t] = (t == 0) ? 0 : lds[t - 1];
}

__global__ void __launch_bounds__(256)
scan3_kernel(int* __restrict__ row_start, const int* __restrict__ blk_sums, int N) {
    int idx = blockIdx.x * blockDim.x + threadIdx.x;
    if (idx < N) row_start[idx] += blk_sums[idx / SCAN_BLK];
}

// ------ fill (atomic-free): csr_src[row_start[dst[e]] + rank[e]] = src[e] ---
__global__ void __launch_bounds__(256)
fill_kernel(const int* __restrict__ src, const int* __restrict__ dst,
            const int* __restrict__ row_start, const unsigned short* __restrict__ rank,
            int* __restrict__ csr_src, int E) {
    int e = blockIdx.x * blockDim.x + threadIdx.x;
    if (e >= E) return;
    csr_src[row_start[dst[e]] + (int)rank[e]] = src[e];
}

// ---------------- xbf: x -> bf16 --------------------------------------------
__global__ void __launch_bounds__(256)
xbf_kernel(const float* __restrict__ x, unsigned short* __restrict__ xbf, long n4) {
    long i = (long)blockIdx.x * 256 + threadIdx.x;
    if (i >= n4) return;
    float4 v = *(const float4*)(x + i * 4);
    ushort4 o;
    o.x = f2bf(v.x); o.y = f2bf(v.y); o.z = f2bf(v.z); o.w = f2bf(v.w);
    *(ushort4*)(xbf + i * 4) = o;
}

// ------- prep: pack [W1l;W1r] -> Bp1 (256x256) and [W2l|W2r] -> Bp2 (256x96) -
__global__ void __launch_bounds__(256)
prep_kernel(const float* __restrict__ W1l, const float* __restrict__ W1r,
            const float* __restrict__ W2l, const float* __restrict__ W2r,
            unsigned short* __restrict__ Bp1, unsigned short* __restrict__ Bp2) {
    int idx = blockIdx.x * 256 + threadIdx.x;
    if (idx < 256 * 256) {
        int k = idx >> 8, c = idx & 255;
        float v = (k < 128) ? W1l[k * 256 + c] : W1r[(k - 128) * 256 + c];
        Bp1[((k >> 5) * 256 + c) * 32 + ((k & 31) >> 3) * 8 + (k & 7)] = f2bf(v);
    } else {
        int j = idx - 65536;
        if (j < 256 * 96) {
            int k = j / 96, c = j % 96;
            float v = 0.0f;
            if (c < 41) v = W2l[k * 41 + c];
            else if (c >= 48 && c < 89) v = W2r[k * 41 + (c - 48)];
            Bp2[((k >> 5) * 96 + c) * 32 + ((k & 31) >> 3) * 8 + (k & 7)] = f2bf(v);
        }
    }
}

// ------- gather1: aggm_bf[n] = bf16(mean_{s} xbf[s]), unroll-8 MLP ----------
__global__ void __launch_bounds__(256)
gather1_kernel(const unsigned short* __restrict__ xbf,
               const int* __restrict__ row_start, const int* __restrict__ deg_i,
               const int* __restrict__ csr_src, unsigned short* __restrict__ aggm,
               int N) {
    int wid = (blockIdx.x * 256 + threadIdx.x) >> 6;
    int lane = threadIdx.x & 63;
    if (wid >= N) return;
    int rs = row_start[wid];
    int d = deg_i[wid];
    const unsigned* xp = (const unsigned*)xbf;
    float sl[8], sh[8];
#pragma unroll
    for (int j = 0; j < 8; ++j) { sl[j] = 0.f; sh[j] = 0.f; }
    int i = 0;
    for (; i + 8 <= d; i += 8) {
        int s[8];
#pragma unroll
        for (int j = 0; j < 8; ++j) s[j] = csr_src[rs + i + j];
        unsigned u[8];
#pragma unroll
        for (int j = 0; j < 8; ++j) u[j] = xp[(size_t)s[j] * 64 + lane];
#pragma unroll
        for (int j = 0; j < 8; ++j) {
            sl[j] += bf2f((unsigned short)u[j]);
            sh[j] += bf2f((unsigned short)(u[j] >> 16));
        }
    }
    for (; i + 4 <= d; i += 4) {
        int s[4];
#pragma unroll
        for (int j = 0; j < 4; ++j) s[j] = csr_src[rs + i + j];
        unsigned u[4];
#pragma unroll
        for (int j = 0; j < 4; ++j) u[j] = xp[(size_t)s[j] * 64 + lane];
#pragma unroll
        for (int j = 0; j < 4; ++j) {
            sl[j] += bf2f((unsigned short)u[j]);
            sh[j] += bf2f((unsigned short)(u[j] >> 16));
        }
    }
    for (; i < d; ++i) {
        unsigned u0 = xp[(size_t)csr_src[rs + i] * 64 + lane];
        sl[0] += bf2f((unsigned short)u0);
        sh[0] += bf2f((unsigned short)(u0 >> 16));
    }
    float ax = ((sl[0] + sl[1]) + (sl[2] + sl[3])) + ((sl[4] + sl[5]) + (sl[6] + sl[7]));
    float ay = ((sh[0] + sh[1]) + (sh[2] + sh[3])) + ((sh[4] + sh[5]) + (sh[6] + sh[7]));
    float inv = 1.0f / fmaxf((float)d, 1.0f);
    unsigned o = ((unsigned)f2bf(ay * inv) << 16) | (unsigned)f2bf(ax * inv);
    ((unsigned*)aggm)[(size_t)wid * 64 + lane] = o;
}

// ------- mgemm1: h1 = bf16(relu([aggm|xbf] @ Bp1 + b1)), MFMA ---------------
__global__ void __launch_bounds__(256)
mgemm1_kernel(const unsigned short* __restrict__ aggm,
              const unsigned short* __restrict__ xbf,
              const unsigned short* __restrict__ Bp1, const float* __restrict__ b1,
              unsigned short* __restrict__ h1, int N) {
    __shared__ __align__(16) unsigned short alds[64 * LDA];
    int n0 = blockIdx.x * 64;
    int t = threadIdx.x;
#pragma unroll
    for (int i = 0; i < 8; ++i) {
        int cid = t + i * 256;
        int row = cid >> 5, c16 = cid & 31;
        int gr = n0 + row;
        uint4 v = make_uint4(0, 0, 0, 0);
        if (gr < N) {
            const unsigned short* srcp = (c16 < 16)
                ? (aggm + (size_t)gr * 128 + c16 * 8)
                : (xbf  + (size_t)gr * 128 + (c16 - 16) * 8);
            v = *(const uint4*)srcp;
        }
        *(uint4*)&alds[row * LDA + c16 * 8] = v;
    }
    __syncthreads();
    int wid = t >> 6, lane = t & 63;
    int l15 = lane & 15, g = lane >> 4;
    int col0 = wid * 64;
    f32x4 acc[4][4];
#pragma unroll
    for (int mf = 0; mf < 4; ++mf)
#pragma unroll
        for (int nf = 0; nf < 4; ++nf) acc[mf][nf] = (f32x4)(0.0f);
    for (int ks = 0; ks < 8; ++ks) {
        short8 af[4], bfr[4];
#pragma unroll
        for (int mf = 0; mf < 4; ++mf)
            af[mf] = *(const short8*)&alds[(mf * 16 + l15) * LDA + ks * 32 + g * 8];
#pragma unroll
        for (int nf = 0; nf < 4; ++nf)
            bfr[nf] = *(const short8*)&Bp1[((size_t)ks * 256 + col0 + nf * 16 + l15) * 32 + g * 8];
#pragma unroll
        for (int mf = 0; mf < 4; ++mf)
#pragma unroll
            for (int nf = 0; nf < 4; ++nf)
                acc[mf][nf] = __builtin_amdgcn_mfma_f32_16x16x32_bf16(
                    af[mf], bfr[nf], acc[mf][nf], 0, 0, 0);
    }
    float bc[4];
#pragma unroll
    for (int nf = 0; nf < 4; ++nf) bc[nf] = b1[col0 + nf * 16 + l15];
#pragma unroll
    for (int mf = 0; mf < 4; ++mf) {
        int rowb = n0 + mf * 16 + g * 4;
#pragma unroll
        for (int r = 0; r < 4; ++r) {
            int row = rowb + r;
            if (row < N) {
#pragma unroll
                for (int nf = 0; nf < 4; ++nf)
                    h1[(size_t)row * 256 + col0 + nf * 16 + l15] =
                        f2bf(fmaxf(acc[mf][nf][r] + bc[nf], 0.0f));
            }
        }
    }
}

// ------- mgemm2: zb = bf16(h1@W2l) ; rbuf = h1@W2r + b2 ---------------------
__global__ void __launch_bounds__(256)
mgemm2_kernel(const unsigned short* __restrict__ h1,
              const unsigned short* __restrict__ Bp2, const float* __restrict__ b2,
              unsigned short* __restrict__ zb, float* __restrict__ rbuf, int N) {
    __shared__ __align__(16) unsigned short alds[64 * LDA];
    int n0 = blockIdx.x * 64;
    int t = threadIdx.x;
#pragma unroll
    for (int i = 0; i < 8; ++i) {
        int cid = t + i * 256;
        int row = cid >> 5, c16 = cid & 31;
        int gr = n0 + row;
        uint4 v = make_uint4(0, 0, 0, 0);
        if (gr < N) v = *(const uint4*)(h1 + (size_t)gr * 256 + c16 * 8);
        *(uint4*)&alds[row * LDA + c16 * 8] = v;
    }
    __syncthreads();
    int wid = t >> 6, lane = t & 63;
    int l15 = lane & 15, g = lane >> 4;
    int wr = wid >> 1, wc = wid & 1;
    f32x4 acc[2][3];
#pragma unroll
    for (int mf = 0; mf < 2; ++mf)
#pragma unroll
        for (int nf = 0; nf < 3; ++nf) acc[mf][nf] = (f32x4)(0.0f);
    for (int ks = 0; ks < 8; ++ks) {
        short8 af[2], bfr[3];
#pragma unroll
        for (int mf = 0; mf < 2; ++mf)
            af[mf] = *(const short8*)&alds[(wr * 32 + mf * 16 + l15) * LDA + ks * 32 + g * 8];
#pragma unroll
        for (int nf = 0; nf < 3; ++nf)
            bfr[nf] = *(const short8*)&Bp2[((size_t)ks * 96 + wc * 48 + nf * 16 + l15) * 32 + g * 8];
#pragma unroll
        for (int mf = 0; mf < 2; ++mf)
#pragma unroll
            for (int nf = 0; nf < 3; ++nf)
                acc[mf][nf] = __builtin_amdgcn_mfma_f32_16x16x32_bf16(
                    af[mf], bfr[nf], acc[mf][nf], 0, 0, 0);
    }
#pragma unroll
    for (int nf = 0; nf < 3; ++nf) {
        int col = wc * 48 + nf * 16 + l15;
        float bb = (col >= 48 && col < 89) ? b2[col - 48] : 0.0f;
#pragma unroll
        for (int mf = 0; mf < 2; ++mf) {
            int rowb = n0 + wr * 32 + mf * 16 + g * 4;
#pragma unroll
            for (int r = 0; r < 4; ++r) {
                int row = rowb + r;
                if (row < N) {
                    float v = acc[mf][nf][r];
                    if (col < 41)                   zb[(size_t)row * CPAD + col] = f2bf(v);
                    else if (col >= 48 && col < 89) rbuf[(size_t)row * CPAD + (col - 48)] = v + bb;
                }
            }
        }
    }
}

// -- gather2+final: 4 nodes/wave (16 lanes each, uint2 = 4 classes), unroll-4
__global__ void __launch_bounds__(256)
gather2_kernel(const uint2* __restrict__ zp, const float* __restrict__ rbuf,
               const int* __restrict__ row_start, const int* __restrict__ deg_i,
               const int* __restrict__ csr_src, float* __restrict__ out, int N) {
    int tid = blockIdx.x * 256 + threadIdx.x;
    int nid = tid >> 4;
    int l = tid & 15;
    if (nid >= N) return;
    int rs = row_start[nid];
    int d = deg_i[nid];
    float a[4][4];
#pragma unroll
    for (int j = 0; j < 4; ++j)
#pragma unroll
        for (int k = 0; k < 4; ++k) a[j][k] = 0.f;
    int i = 0;
    for (; i + 4 <= d; i += 4) {
        int s[4];
#pragma unroll
        for (int j = 0; j < 4; ++j) s[j] = csr_src[rs + i + j];
        uint2 u[4];
#pragma unroll
        for (int j = 0; j < 4; ++j) u[j] = zp[(size_t)s[j] * 16 + l];
#pragma unroll
        for (int j = 0; j < 4; ++j) {
            a[j][0] += bf2f((unsigned short)u[j].x);
            a[j][1] += bf2f((unsigned short)(u[j].x >> 16));
            a[j][2] += bf2f((unsigned short)u[j].y);
            a[j][3] += bf2f((unsigned short)(u[j].y >> 16));
        }
    }
    for (; i < d; ++i) {
        uint2 u0 = zp[(size_t)csr_src[rs + i] * 16 + l];
        a[0][0] += bf2f((unsigned short)u0.x);
        a[0][1] += bf2f((unsigned short)(u0.x >> 16));
        a[0][2] += bf2f((unsigned short)u0.y);
        a[0][3] += bf2f((unsigned short)(u0.y >> 16));
    }
    float inv = 1.0f / fmaxf((float)d, 1.0f);
    float4 rb = *(const float4*)&rbuf[(size_t)nid * CPAD + 4 * l];
    float rbv[4] = {rb.x, rb.y, rb.z, rb.w};
    float v[4];
#pragma unroll
    for (int k = 0; k < 4; ++k) {
        int col = 4 * l + k;
        v[k] = (col < CLASSES)
             ? ((a[0][k] + a[1][k]) + (a[2][k] + a[3][k])) * inv + rbv[k]
             : -INFINITY;
    }
    float m = fmaxf(fmaxf(v[0], v[1]), fmaxf(v[2], v[3]));
#pragma unroll
    for (int off = 8; off; off >>= 1) m = fmaxf(m, __shfl_xor(m, off, 16));
    float s = 0.f;
#pragma unroll
    for (int k = 0; k < 4; ++k)
        s += (4 * l + k < CLASSES) ? expf(v[k] - m) : 0.0f;
#pragma unroll
    for (int off = 8; off; off >>= 1) s += __shfl_xor(s, off, 16);
    float lse = m + logf(s);
#pragma unroll
    for (int k = 0; k < 4; ++k) {
        int col = 4 * l + k;
        if (col < CLASSES) out[(size_t)nid * CLASSES + col] = v[k] - lse;
    }
}

extern "C" void kernel_launch(void* const* d_in, const int* in_sizes, int n_in,
                              void* d_out, int out_size, void* d_ws, size_t ws_size,
                              hipStream_t stream) {
    const float* x   = (const float*)d_in[0];
    const int*   ei  = (const int*)d_in[1];
    const float* W1l = (const float*)d_in[2];
    const float* W1r = (const float*)d_in[3];
    const float* b1  = (const float*)d_in[4];
    const float* W2l = (const float*)d_in[5];
    const float* W2r = (const float*)d_in[6];
    const float* b2  = (const float*)d_in[7];
    float* out = (float*)d_out;

    int N = in_sizes[0] / IN_FEATS;
    int E = in_sizes[1] / 2;
    const int* src = ei;
    const int* dst = ei + E;

    // ints: [deg_i N][blk_sums 256][row_start N][csr_src E]  then rank (u16, E)
    int* ws_i      = (int*)d_ws;
    int* deg_i     = ws_i;
    int* blk_sums  = ws_i + (size_t)N;
    int* row_start = ws_i + (size_t)N + 256;
    int* csr_src   = ws_i + (size_t)2 * N + 256;
    unsigned short* rank = (unsigned short*)(csr_src + (size_t)E);
    size_t int_bytes = ((size_t)2 * N + 256 + (size_t)E) * sizeof(int)
                     + (size_t)E * sizeof(unsigned short);
    char* p = (char*)d_ws + ((int_bytes + 15) & ~(size_t)15);
    unsigned short* xbf  = (unsigned short*)p;            p += (size_t)N * 128 * 2;
    unsigned short* aggm = (unsigned short*)p;            p += (size_t)N * 128 * 2;
    unsigned short* h1   = (unsigned short*)p;            p += (size_t)N * 256 * 2;
    unsigned short* Bp1  = (unsigned short*)p;            p += 65536 * 2;
    unsigned short* Bp2  = (unsigned short*)p;            p += 24576 * 2;
    unsigned short* zb   = (unsigned short*)p;            p += (size_t)N * CPAD * 2;
    float* rbuf = (float*)p;

    hipMemsetAsync(deg_i, 0, ((size_t)N + 256) * sizeof(int), stream);

    hist_kernel<<<(E + 255) / 256, 256, 0, stream>>>(dst, deg_i, rank, E);

    int nscan = (N + SCAN_BLK - 1) / SCAN_BLK;
    scan1_kernel<<<nscan, 256, 0, stream>>>(deg_i, row_start, blk_sums, N);
    scan2_kernel<<<1, 256, 0, stream>>>(blk_sums, nscan);
    scan3_kernel<<<(N + 255) / 256, 256, 0, stream>>>(row_start, blk_sums, N);

    fill_kernel<<<(E + 255) / 256, 256, 0, stream>>>(src, dst, row_start, rank,
                                                     csr_src, E);

    long n4 = (long)N * 128 / 4;
    xbf_kernel<<<(int)((n4 + 255) / 256), 256, 0, stream>>>(x, xbf, n4);
    prep_kernel<<<(65536 + 24576 + 255) / 256, 256, 0, stream>>>(
        W1l, W1r, W2l, W2r, Bp1, Bp2);

    {
        long long threads = (long long)N * 64;
        gather1_kernel<<<(int)((threads + 255) / 256), 256, 0, stream>>>(
            xbf, row_start, deg_i, csr_src, aggm, N);
    }
    int gblocks = (N + 63) / 64;
    mgemm1_kernel<<<gblocks, 256, 0, stream>>>(aggm, xbf, Bp1, b1, h1, N);
    mgemm2_kernel<<<gblocks, 256, 0, stream>>>(h1, Bp2, b2, zb, rbuf, N);
    {
        long long threads = (long long)N * 16;
        gather2_kernel<<<(int)((threads + 255) / 256), 256, 0, stream>>>(
            (const uint2*)zb, rbuf, row_start, deg_i, csr_src, out, N);
    }
}